// Round 1
// baseline (74.498 us; speedup 1.0000x reference)
//
#include <hip/hip_runtime.h>

#define NB   1024   // batch
#define LSQ  200    // sequence length
#define DD   16     // embedding dim
#define LT   10
#define LSC  5
#define NC   100

__global__ __launch_bounds__(256) void hin_kernel(
    const int*   __restrict__ user_idx,       // (B,1)
    const int*   __restrict__ user_sequence,  // (B,200)
    const int*   __restrict__ user_teachers,  // (B,10)
    const int*   __restrict__ user_school,    // (B,5)
    const float* __restrict__ user_len_teacher, // (B,1)
    const float* __restrict__ user_len_school,  // (B,1)
    const int*   __restrict__ course_set,     // (B,100)
    const float* __restrict__ user_table,     // (100001,16)
    const float* __restrict__ course_table,   // (10001,16)
    const float* __restrict__ teacher_table,  // (5001,16)
    const float* __restrict__ school_table,   // (3001,16)
    const float* __restrict__ Qw, const float* __restrict__ Qb,
    const float* __restrict__ Kw, const float* __restrict__ Kb,
    const float* __restrict__ g1w, const float* __restrict__ g1b,
    const float* __restrict__ g2w, const float* __restrict__ g2b,
    float*       __restrict__ out)            // (B,100)
{
    __shared__ float x [LSQ * DD];   // seq embeddings, (200,16) row-major
    __shared__ float kf[LSQ * DD];   // K flat, (200,16) row-major == reshaped (16,200)
    __shared__ float qt[DD * LSQ];   // Q transposed: qt[d*200 + row]
    __shared__ float w_Qw[DD*DD], w_Kw[DD*DD], w_Qb[DD], w_Kb[DD];
    __shared__ float red[4][DD];
    __shared__ float hvec[2*DD];
    __shared__ float hid[DD];
    __shared__ float uf[DD];

    const int b = blockIdx.x;
    const int t = threadIdx.x;

    // ---- stage weights ----
    if (t < DD*DD) { w_Qw[t] = Qw[t]; w_Kw[t] = Kw[t]; }
    if (t < DD)    { w_Qb[t] = Qb[t]; w_Kb[t] = Kb[t]; }

    // ---- gather x = course_table[user_sequence[b]] ----
    for (int e = t; e < LSQ*DD; e += 256) {
        const int l = e >> 4, d = e & 15;
        const int idx = user_sequence[b*LSQ + l];
        x[e] = course_table[idx*DD + d];
    }
    __syncthreads();

    // ---- cooperative Q (transposed) and K (flat) ----
    for (int e = t; e < LSQ*DD; e += 256) {
        const int l = e >> 4, d = e & 15;
        float aq = w_Qb[d], ak = w_Kb[d];
        #pragma unroll
        for (int k = 0; k < DD; k++) {
            const float xv = x[l*DD + k];           // broadcast within 16-lane group
            aq = fmaf(xv, w_Qw[k*DD + d], aq);
            ak = fmaf(xv, w_Kw[k*DD + d], ak);
        }
        qt[d*LSQ + l] = fmaxf(aq, 0.f);
        kf[e]         = fmaxf(ak, 0.f);
    }
    __syncthreads();

    // ---- per-thread attention row (single pass; |s| tiny so no max-sub needed) ----
    const int row = t;
    float q[DD];
    float acc[DD];
    #pragma unroll
    for (int k = 0; k < DD; k++) acc[k] = 0.f;
    float lsum = 0.f;

    if (row < LSQ) {
        #pragma unroll
        for (int d = 0; d < DD; d++) q[d] = qt[d*LSQ + row];  // conflict-free

        for (int j0 = 0; j0 < LSQ; j0 += 4) {
            float s0 = 0.f, s1 = 0.f, s2 = 0.f, s3 = 0.f;
            #pragma unroll
            for (int p = 0; p < DD; p++) {
                const float4 kv = *(const float4*)&kf[p*LSQ + j0];  // uniform broadcast
                const float qp = q[p];
                s0 = fmaf(qp, kv.x, s0);
                s1 = fmaf(qp, kv.y, s1);
                s2 = fmaf(qp, kv.z, s2);
                s3 = fmaf(qp, kv.w, s3);
            }
            s0 *= 0.25f; s1 *= 0.25f; s2 *= 0.25f; s3 *= 0.25f;  // /sqrt(16)
            if (j0 + 0 == row) s0 = 1e-32f;
            if (j0 + 1 == row) s1 = 1e-32f;
            if (j0 + 2 == row) s2 = 1e-32f;
            if (j0 + 3 == row) s3 = 1e-32f;
            const float p0 = __expf(s0), p1 = __expf(s1),
                        p2 = __expf(s2), p3 = __expf(s3);
            lsum += (p0 + p1) + (p2 + p3);
            #pragma unroll
            for (int g = 0; g < 4; g++) {
                const float4 x0 = *(const float4*)&x[(j0+0)*DD + g*4];
                const float4 x1 = *(const float4*)&x[(j0+1)*DD + g*4];
                const float4 x2 = *(const float4*)&x[(j0+2)*DD + g*4];
                const float4 x3 = *(const float4*)&x[(j0+3)*DD + g*4];
                acc[g*4+0] = fmaf(p0,x0.x, fmaf(p1,x1.x, fmaf(p2,x2.x, fmaf(p3,x3.x, acc[g*4+0]))));
                acc[g*4+1] = fmaf(p0,x0.y, fmaf(p1,x1.y, fmaf(p2,x2.y, fmaf(p3,x3.y, acc[g*4+1]))));
                acc[g*4+2] = fmaf(p0,x0.z, fmaf(p1,x1.z, fmaf(p2,x2.z, fmaf(p3,x3.z, acc[g*4+2]))));
                acc[g*4+3] = fmaf(p0,x0.w, fmaf(p1,x1.w, fmaf(p2,x2.w, fmaf(p3,x3.w, acc[g*4+3]))));
            }
        }
    }

    // ---- reduce mean over rows: sum_i acc_i/lsum_i, then /200 ----
    const float inv_l = (row < LSQ) ? (1.0f / lsum) : 0.0f;
    const int wave = t >> 6, lane = t & 63;
    #pragma unroll
    for (int k = 0; k < DD; k++) {
        float v = acc[k] * inv_l;
        #pragma unroll
        for (int off = 32; off > 0; off >>= 1) v += __shfl_xor(v, off);
        if (lane == 0) red[wave][k] = v;
    }
    __syncthreads();

    // ---- finish user vector (16 threads) ----
    if (t < DD) {
        const float seq = (red[0][t] + red[1][t] + red[2][t] + red[3][t]) * (1.0f / LSQ);
        float uts = 0.f;
        #pragma unroll
        for (int i = 0; i < LT; i++)
            uts += teacher_table[user_teachers[b*LT + i]*DD + t];
        float uss = 0.f;
        #pragma unroll
        for (int i = 0; i < LSC; i++)
            uss += school_table[user_school[b*LSC + i]*DD + t];
        const float ut = uts / user_len_teacher[b];
        const float us = uss / user_len_school[b];
        const float agg = (seq + ut + us) * (1.0f / 3.0f);
        hvec[t]      = user_table[user_idx[b]*DD + t];
        hvec[DD + t] = agg;
    }
    __syncthreads();
    if (t < DD) {
        float a1 = g1b[t];
        #pragma unroll
        for (int k = 0; k < 2*DD; k++) a1 = fmaf(hvec[k], g1w[k*DD + t], a1);
        hid[t] = fmaxf(a1, 0.f);
    }
    __syncthreads();
    if (t < DD) {
        float a2 = g2b[t];
        #pragma unroll
        for (int k = 0; k < DD; k++) a2 = fmaf(hid[k], g2w[k*DD + t], a2);
        uf[t] = a2;
    }
    __syncthreads();

    // ---- epilogue: out[b,c] = dot(user_final, course_table[course_set[b,c]]) ----
    for (int c = t; c < NC; c += 256) {
        const int ci = course_set[b*NC + c];
        const float* ce = &course_table[ci*DD];
        float s = 0.f;
        #pragma unroll
        for (int g = 0; g < 4; g++) {
            const float4 cv = *(const float4*)&ce[g*4];
            const float4 uv = *(const float4*)&uf[g*4];
            s += cv.x*uv.x + cv.y*uv.y + cv.z*uv.z + cv.w*uv.w;
        }
        out[b*NC + c] = s;
    }
}

extern "C" void kernel_launch(void* const* d_in, const int* in_sizes, int n_in,
                              void* d_out, int out_size, void* d_ws, size_t ws_size,
                              hipStream_t stream) {
    const int*   user_idx         = (const int*)  d_in[0];
    const int*   user_sequence    = (const int*)  d_in[1];
    const int*   user_teachers    = (const int*)  d_in[2];
    const int*   user_school      = (const int*)  d_in[3];
    // d_in[4] = user_len_seq (unused by reference)
    const float* user_len_teacher = (const float*)d_in[5];
    const float* user_len_school  = (const float*)d_in[6];
    const int*   course_set       = (const int*)  d_in[7];
    // d_in[8..12] dead code in reference (course_user/school/teacher, lens)
    const float* user_table       = (const float*)d_in[13];
    const float* course_table     = (const float*)d_in[14];
    const float* teacher_table    = (const float*)d_in[15];
    const float* school_table     = (const float*)d_in[16];
    const float* Qw  = (const float*)d_in[17];
    const float* Qb  = (const float*)d_in[18];
    const float* Kw  = (const float*)d_in[19];
    const float* Kb  = (const float*)d_in[20];
    const float* g1w = (const float*)d_in[21];
    const float* g1b = (const float*)d_in[22];
    const float* g2w = (const float*)d_in[23];
    const float* g2b = (const float*)d_in[24];
    // d_in[25..27] caw1/cab1/caw2: dead code

    float* outp = (float*)d_out;

    hipLaunchKernelGGL(hin_kernel, dim3(NB), dim3(256), 0, stream,
                       user_idx, user_sequence, user_teachers, user_school,
                       user_len_teacher, user_len_school, course_set,
                       user_table, course_table, teacher_table, school_table,
                       Qw, Qb, Kw, Kb, g1w, g1b, g2w, g2b, outp);
}

// Round 2
// 33.560 us; speedup vs baseline: 2.2198x; 2.2198x over previous
//
#include <hip/hip_runtime.h>
#include <hip/hip_bf16.h>

#define NBATCH 1024
#define L      200     // sequence length
#define DD     16      // embedding dim
#define LTT    10
#define LSCH   5
#define NCC    100

#define LPAD   208     // 13 m-tiles of 16
#define JPAD   224     // 14 j-tiles of 16 (7 pairs of 32)
#define XT_S   232     // xt row stride (bf16 elems), 464B: 16B-aligned, ~2-way banks
#define QK_S   24      // qb/kt row stride, 48B: 16B-aligned, ~2-way banks
#define PT_S   40      // p-tile row stride, 80B: 16B-aligned, ~2-way banks

typedef __bf16 bf16_8 __attribute__((ext_vector_type(8)));
typedef float  f32x4  __attribute__((ext_vector_type(4)));

__global__ __launch_bounds__(256) void hin_kernel(
    const int*   __restrict__ user_idx,
    const int*   __restrict__ user_sequence,
    const int*   __restrict__ user_teachers,
    const int*   __restrict__ user_school,
    const float* __restrict__ user_len_teacher,
    const float* __restrict__ user_len_school,
    const int*   __restrict__ course_set,
    const float* __restrict__ user_table,
    const float* __restrict__ course_table,
    const float* __restrict__ teacher_table,
    const float* __restrict__ school_table,
    const float* __restrict__ Qw, const float* __restrict__ Qb,
    const float* __restrict__ Kw, const float* __restrict__ Kb,
    const float* __restrict__ g1w, const float* __restrict__ g1b,
    const float* __restrict__ g2w, const float* __restrict__ g2b,
    float*       __restrict__ out)
{
    __shared__ __align__(16) __bf16 xt[DD * XT_S];     // [d][j], cols 200..231 zeroed
    __shared__ __align__(16) __bf16 qb[LPAD * QK_S];   // [row][p]
    __shared__ __align__(16) __bf16 kt[JPAD * QK_S];   // [j][p], rows 200..223 zeroed
    __shared__ __align__(16) __bf16 pt[4][16 * PT_S];  // per-wave P pair-tile (16 x 32)
    __shared__ float wQ[DD*DD], wK[DD*DD], bQv[DD], bKv[DD];
    __shared__ int   sidx[L];
    __shared__ float red[4][DD];
    __shared__ float hvec[2*DD], hid[DD], uf[DD];

    const int b = blockIdx.x;
    const int t = threadIdx.x;

    // ---------------- phase 0: stage weights, indices, zero pads ----------------
    wQ[t] = Qw[t];                         // t covers exactly 256 = DD*DD
    wK[t] = Kw[t];
    if (t < DD) { bQv[t] = Qb[t]; bKv[t] = Kb[t]; }
    if (t < L)  sidx[t] = user_sequence[b*L + t];
    // zero xt cols 200..231 (16 rows x 32)
    for (int e = t; e < DD*32; e += 256)
        xt[(e >> 5)*XT_S + 200 + (e & 31)] = (__bf16)0.f;
    // zero kt rows 200..223 (24 rows x QK_S)
    for (int e = t; e < 24*QK_S; e += 256)
        kt[(200 + e/QK_S)*QK_S + (e % QK_S)] = (__bf16)0.f;
    __syncthreads();

    // ---------------- phase 1: gather x -> xt (transposed, bf16) ----------------
    for (int e = t; e < L*DD; e += 256) {
        const int l = e >> 4, d = e & 15;
        const float v = course_table[sidx[l]*DD + d];
        xt[d*XT_S + l] = (__bf16)v;
    }
    __syncthreads();

    // ---------------- phase 2: Q,K compute -> qb, kt (bf16) ----------------
    for (int e = t; e < LPAD*DD; e += 256) {
        const int l = e >> 4, d = e & 15;
        float aq = bQv[d], ak = bKv[d];
        #pragma unroll
        for (int k = 0; k < DD; k++) {
            const float xv = (float)xt[k*XT_S + l];   // zero for l>=200
            aq = fmaf(xv, wQ[k*DD + d], aq);
            ak = fmaf(xv, wK[k*DD + d], ak);
        }
        qb[l*QK_S + d] = (__bf16)fmaxf(aq, 0.f);
        if (l < L) {
            const int f = e;                 // flat index into (200,16) K matrix
            const int p = f / 200;           // reshape (200,16)->(16,200): row p
            const int j = f - p*200;         // col j
            kt[j*QK_S + p] = (__bf16)fmaxf(ak, 0.f);
        }
    }
    __syncthreads();

    // ---------------- phase 3: flash attention via MFMA ----------------
    const int w    = t >> 6;
    const int lane = t & 63;
    const int grp  = lane >> 4;
    const int li   = lane & 15;
    __bf16* ptw = pt[w];

    bf16_8 zero8;
    #pragma unroll
    for (int i = 0; i < 8; i++) zero8[i] = (__bf16)0.f;

    float wsum = 0.f;

    for (int mt = w; mt < 13; mt += 4) {
        const int m0 = mt * 16;
        // A fragment: Q[m0+li][k], k=grp*8+e (k>=16 -> 0)
        bf16_8 aq = zero8;
        if (grp < 2) aq = *(const bf16_8*)&qb[(m0 + li)*QK_S + grp*8];

        f32x4 accv = {0.f, 0.f, 0.f, 0.f};
        float ps[4] = {0.f, 0.f, 0.f, 0.f};

        for (int jp = 0; jp < 7; jp++) {
            #pragma unroll
            for (int h = 0; h < 2; h++) {
                const int jt = jp*2 + h;
                // B fragment: kt[jt*16+li][k], k=grp*8+e (k>=16 -> 0)
                bf16_8 bk = zero8;
                if (grp < 2) bk = *(const bf16_8*)&kt[(jt*16 + li)*QK_S + grp*8];
                f32x4 zc = {0.f, 0.f, 0.f, 0.f};
                f32x4 s = __builtin_amdgcn_mfma_f32_16x16x32_bf16(aq, bk, zc, 0, 0, 0);
                const int gcol = jt*16 + li;
                #pragma unroll
                for (int r = 0; r < 4; r++) {
                    const int grow = m0 + grp*4 + r;
                    float pv;
                    if (gcol < L) pv = (gcol == grow) ? 1.0f : __expf(s[r] * 0.25f);
                    else          pv = 0.f;
                    ps[r] += pv;
                    ptw[(grp*4 + r)*PT_S + h*16 + li] = (__bf16)pv;
                }
            }
            // PV: A = P (16 x 32 pair tile), B = x[j][d] from xt
            bf16_8 pa = *(const bf16_8*)&ptw[li*PT_S + grp*8];
            bf16_8 xb = *(const bf16_8*)&xt[li*XT_S + jp*32 + grp*8];
            accv = __builtin_amdgcn_mfma_f32_16x16x32_bf16(pa, xb, accv, 0, 0, 0);
        }

        // row sums (softmax denominators) across the 16 cols-lanes, then normalize
        #pragma unroll
        for (int r = 0; r < 4; r++) {
            float v = ps[r];
            v += __shfl_xor(v, 1);
            v += __shfl_xor(v, 2);
            v += __shfl_xor(v, 4);
            v += __shfl_xor(v, 8);
            const int grow = m0 + grp*4 + r;
            const float a = accv[r] * __builtin_amdgcn_rcpf(v);
            wsum += (grow < L) ? a : 0.f;
        }
    }
    // sum across the 4 lane-groups (rows) -> per-d totals
    wsum += __shfl_xor(wsum, 16);
    wsum += __shfl_xor(wsum, 32);
    if (lane < DD) red[w][lane] = wsum;
    __syncthreads();

    // ---------------- phase 4: user vector + MLP ----------------
    if (t < DD) {
        const float seq = (red[0][t] + red[1][t] + red[2][t] + red[3][t]) * (1.0f / L);
        float uts = 0.f;
        #pragma unroll
        for (int i = 0; i < LTT; i++)
            uts += teacher_table[user_teachers[b*LTT + i]*DD + t];
        float uss = 0.f;
        #pragma unroll
        for (int i = 0; i < LSCH; i++)
            uss += school_table[user_school[b*LSCH + i]*DD + t];
        const float ut = uts / user_len_teacher[b];
        const float us = uss / user_len_school[b];
        const float agg = (seq + ut + us) * (1.0f / 3.0f);
        hvec[t]      = user_table[user_idx[b]*DD + t];
        hvec[DD + t] = agg;
    }
    __syncthreads();
    if (t < DD) {
        float a1 = g1b[t];
        #pragma unroll
        for (int k = 0; k < 2*DD; k++) a1 = fmaf(hvec[k], g1w[k*DD + t], a1);
        hid[t] = fmaxf(a1, 0.f);
    }
    __syncthreads();
    if (t < DD) {
        float a2 = g2b[t];
        #pragma unroll
        for (int k = 0; k < DD; k++) a2 = fmaf(hid[k], g2w[k*DD + t], a2);
        uf[t] = a2;
    }
    __syncthreads();

    // ---------------- epilogue: out[b,c] = dot(user_final, course_emb) ----------------
    for (int c = t; c < NCC; c += 256) {
        const int ci = course_set[b*NCC + c];
        const float* ce = &course_table[ci*DD];
        float s = 0.f;
        #pragma unroll
        for (int g = 0; g < 4; g++) {
            const float4 cv = *(const float4*)&ce[g*4];
            const float4 uv = *(const float4*)&uf[g*4];
            s += cv.x*uv.x + cv.y*uv.y + cv.z*uv.z + cv.w*uv.w;
        }
        out[b*NCC + c] = s;
    }
}

extern "C" void kernel_launch(void* const* d_in, const int* in_sizes, int n_in,
                              void* d_out, int out_size, void* d_ws, size_t ws_size,
                              hipStream_t stream) {
    const int*   user_idx         = (const int*)  d_in[0];
    const int*   user_sequence    = (const int*)  d_in[1];
    const int*   user_teachers    = (const int*)  d_in[2];
    const int*   user_school      = (const int*)  d_in[3];
    const float* user_len_teacher = (const float*)d_in[5];
    const float* user_len_school  = (const float*)d_in[6];
    const int*   course_set       = (const int*)  d_in[7];
    const float* user_table       = (const float*)d_in[13];
    const float* course_table     = (const float*)d_in[14];
    const float* teacher_table    = (const float*)d_in[15];
    const float* school_table     = (const float*)d_in[16];
    const float* Qw  = (const float*)d_in[17];
    const float* Qb  = (const float*)d_in[18];
    const float* Kw  = (const float*)d_in[19];
    const float* Kb  = (const float*)d_in[20];
    const float* g1w = (const float*)d_in[21];
    const float* g1b = (const float*)d_in[22];
    const float* g2w = (const float*)d_in[23];
    const float* g2b = (const float*)d_in[24];

    float* outp = (float*)d_out;

    hipLaunchKernelGGL(hin_kernel, dim3(NBATCH), dim3(256), 0, stream,
                       user_idx, user_sequence, user_teachers, user_school,
                       user_len_teacher, user_len_school, course_set,
                       user_table, course_table, teacher_table, school_table,
                       Qw, Qb, Kw, Kb, g1w, g1b, g2w, g2b, outp);
}

// Round 3
// 32.356 us; speedup vs baseline: 2.3024x; 1.0372x over previous
//
#include <hip/hip_runtime.h>
#include <hip/hip_bf16.h>

#define NBATCH 1024
#define L      200
#define DD     16
#define LTT    10
#define LSCH   5
#define NCC    100

#define XT_S   232   // xt [16][232]  x transposed [d][l], cols 200..231 zero
#define XR_S   24    // xr [208][24]  x row-major [l][d], rows 200..207 zero
#define QB_S   24    // qb [208][24]  Q row-major [l][p]
#define KT_S   24    // kt [208][24]  K-flat row-major [j][p], rows 200..207 zero
#define PT_S   40    // pt [16][40] per wave, P pair-tile rows [prow][c]
#define WT_S   40    // wqt/wkt [16][40], W^T [n][k], k 16..31 zero

typedef __bf16 bf16_8 __attribute__((ext_vector_type(8)));
typedef __bf16 bf16_4 __attribute__((ext_vector_type(4)));
typedef float  f32x4  __attribute__((ext_vector_type(4)));

__global__ __launch_bounds__(256) void hin_kernel(
    const int*   __restrict__ user_idx,
    const int*   __restrict__ user_sequence,
    const int*   __restrict__ user_teachers,
    const int*   __restrict__ user_school,
    const float* __restrict__ user_len_teacher,
    const float* __restrict__ user_len_school,
    const int*   __restrict__ course_set,
    const float* __restrict__ user_table,
    const float* __restrict__ course_table,
    const float* __restrict__ teacher_table,
    const float* __restrict__ school_table,
    const float* __restrict__ Qw, const float* __restrict__ Qb,
    const float* __restrict__ Kw, const float* __restrict__ Kb,
    const float* __restrict__ g1w, const float* __restrict__ g1b,
    const float* __restrict__ g2w, const float* __restrict__ g2b,
    float*       __restrict__ out)
{
    __shared__ __align__(16) __bf16 xt[DD * XT_S];
    __shared__ __align__(16) __bf16 xr[208 * XR_S];
    __shared__ __align__(16) __bf16 qb[208 * QB_S];
    __shared__ __align__(16) __bf16 kt[208 * KT_S];
    __shared__ __align__(16) __bf16 pt[4][16 * PT_S];
    __shared__ __align__(16) __bf16 wqt[DD * WT_S], wkt[DD * WT_S];
    __shared__ float bQv[DD], bKv[DD];
    __shared__ int   sidx[L];
    __shared__ float red[4][DD];
    __shared__ float hvec[2*DD], hid[DD], uf[DD];

    const int b = blockIdx.x;
    const int t = threadIdx.x;
    const int w    = t >> 6;
    const int lane = t & 63;
    const int grp  = lane >> 4;
    const int li   = lane & 15;

    // ---------------- phase 0: weights (transposed, bf16), indices, zero pads ----
    {
        const int k = t >> 4, n = t & 15;          // t covers 16x16
        wqt[n*WT_S + k]      = (__bf16)Qw[k*DD + n];
        wkt[n*WT_S + k]      = (__bf16)Kw[k*DD + n];
        wqt[n*WT_S + 16 + k] = (__bf16)0.f;        // k-pad 16..31
        wkt[n*WT_S + 16 + k] = (__bf16)0.f;
    }
    if (t < DD) { bQv[t] = Qb[t]; bKv[t] = Kb[t]; }
    if (t < L)  sidx[t] = user_sequence[b*L + t];
    for (int e = t; e < DD*32; e += 256)                 // xt cols 200..231
        xt[(e >> 5)*XT_S + 200 + (e & 31)] = (__bf16)0.f;
    if (t < 192) {                                       // kt rows 200..207
        kt[(200 + t/KT_S)*KT_S + (t % KT_S)] = (__bf16)0.f;
        xr[(200 + t/XR_S)*XR_S + (t % XR_S)] = (__bf16)0.f;
    }
    __syncthreads();

    // ---------------- phase 1: gather x -> xr (row-major) + xt (transposed) -----
    for (int e = t; e < 800; e += 256) {
        const int l = e >> 2, dq = e & 3;
        const float4 v = *(const float4*)&course_table[sidx[l]*DD + dq*4];
        bf16_4 x4;
        x4[0] = (__bf16)v.x; x4[1] = (__bf16)v.y;
        x4[2] = (__bf16)v.z; x4[3] = (__bf16)v.w;
        *(bf16_4*)&xr[l*XR_S + dq*4] = x4;
        xt[(dq*4+0)*XT_S + l] = x4[0];
        xt[(dq*4+1)*XT_S + l] = x4[1];
        xt[(dq*4+2)*XT_S + l] = x4[2];
        xt[(dq*4+3)*XT_S + l] = x4[3];
    }
    __syncthreads();

    bf16_8 zero8;
    #pragma unroll
    for (int i = 0; i < 8; i++) zero8[i] = (__bf16)0.f;

    // ---------------- phase 2: Q^T,K^T via MFMA -> qb, kt -----------------------
    {
        float qbias[4], kbias[4];
        #pragma unroll
        for (int r = 0; r < 4; r++) { qbias[r] = bQv[grp*4+r]; kbias[r] = bKv[grp*4+r]; }
        const bf16_8 wq = *(const bf16_8*)&wqt[li*WT_S + grp*8];
        const bf16_8 wk = *(const bf16_8*)&wkt[li*WT_S + grp*8];
        for (int mt = w; mt < 13; mt += 4) {
            const int l0 = mt * 16;
            bf16_8 xf = zero8;
            if (grp < 2) xf = *(const bf16_8*)&xr[(l0+li)*XR_S + grp*8];
            f32x4 zc = {0.f, 0.f, 0.f, 0.f};
            f32x4 qv = __builtin_amdgcn_mfma_f32_16x16x32_bf16(wq, xf, zc, 0, 0, 0);
            f32x4 kv = __builtin_amdgcn_mfma_f32_16x16x32_bf16(wk, xf, zc, 0, 0, 0);
            // lane holds Q[l0+li][grp*4+r] / K[l0+li][grp*4+r]
            bf16_4 qpk;
            #pragma unroll
            for (int r = 0; r < 4; r++)
                qpk[r] = (__bf16)fmaxf(qv[r] + qbias[r], 0.f);
            *(bf16_4*)&qb[(l0+li)*QB_S + grp*4] = qpk;
            // K reshape scatter: f = l*16 + p -> kt[f%200][f/200]
            const int fb = (l0+li)*DD + grp*4;
            const int p0 = fb / 200;
            const int j0 = fb - p0*200;
            #pragma unroll
            for (int r = 0; r < 4; r++)
                kt[(j0+r)*KT_S + p0] = (__bf16)fmaxf(kv[r] + kbias[r], 0.f);
        }
    }
    __syncthreads();

    // ---------------- phase 3: attention (S^T via swapped MFMA) -----------------
    __bf16* ptw = pt[w];
    float wsum = 0.f;

    for (int mt = w; mt < 13; mt += 4) {
        const int m0 = mt * 16;
        bf16_8 qf = zero8;                       // B-frag: Q rows m0..m0+15
        if (grp < 2) qf = *(const bf16_8*)&qb[(m0+li)*QB_S + grp*8];

        f32x4 accv = {0.f, 0.f, 0.f, 0.f};
        float ps = 0.f;

        for (int jp = 0; jp < 7; jp++) {
            #pragma unroll
            for (int h = 0; h < 2; h++) {
                const int jt = jp*2 + h;
                bf16_4 pw;
                if (jt == 13) {                  // cols 208..223 fully OOB
                    #pragma unroll
                    for (int r = 0; r < 4; r++) pw[r] = (__bf16)0.f;
                } else {
                    bf16_8 kf = zero8;           // A-frag: K-flat rows jt*16..+15
                    if (grp < 2) kf = *(const bf16_8*)&kt[(jt*16+li)*KT_S + grp*8];
                    f32x4 zc = {0.f, 0.f, 0.f, 0.f};
                    f32x4 s = __builtin_amdgcn_mfma_f32_16x16x32_bf16(kf, qf, zc, 0, 0, 0);
                    // lane holds S[row=m0+li][col=jt*16+grp*4+r]
                    #pragma unroll
                    for (int r = 0; r < 4; r++) {
                        float pv = __expf(s[r] * 0.25f);
                        if (jt == 12 && grp >= 2) pv = 0.f;           // cols 200..207
                        if (jt == mt && li == grp*4 + r) pv = 1.0f;   // diagonal
                        ps += pv;
                        pw[r] = (__bf16)pv;
                    }
                }
                *(bf16_4*)&ptw[li*PT_S + h*16 + grp*4] = pw;
            }
            // PV: A = P rows (li), B = x[j][d] from xt
            const bf16_8 pa = *(const bf16_8*)&ptw[li*PT_S + grp*8];
            const bf16_8 xb = *(const bf16_8*)&xt[li*XT_S + jp*32 + grp*8];
            accv = __builtin_amdgcn_mfma_f32_16x16x32_bf16(pa, xb, accv, 0, 0, 0);
        }

        // row-sum: ps covers this lane's cols; reduce across grp -> row (m0+li) total
        float tot = ps;
        tot += __shfl_xor(tot, 16);
        tot += __shfl_xor(tot, 32);
        // normalize: accv[r] is O[m0+grp*4+r][li]; need row (m0+grp*4+r) sum
        #pragma unroll
        for (int r = 0; r < 4; r++) {
            const int grow = m0 + grp*4 + r;
            const float dsum = __shfl(tot, grp*4 + r);
            const float a = accv[r] * __builtin_amdgcn_rcpf(dsum);
            wsum += (grow < L) ? a : 0.f;
        }
    }
    // collapse rows: sum over grp -> per-d (li) totals for this wave
    wsum += __shfl_xor(wsum, 16);
    wsum += __shfl_xor(wsum, 32);
    if (lane < DD) red[w][lane] = wsum;
    __syncthreads();

    // ---------------- phase 4: user vector + MLP --------------------------------
    if (t < DD) {
        const float seq = (red[0][t] + red[1][t] + red[2][t] + red[3][t]) * (1.0f / L);
        float uts = 0.f;
        #pragma unroll
        for (int i = 0; i < LTT; i++)
            uts += teacher_table[user_teachers[b*LTT + i]*DD + t];
        float uss = 0.f;
        #pragma unroll
        for (int i = 0; i < LSCH; i++)
            uss += school_table[user_school[b*LSCH + i]*DD + t];
        const float ut = uts / user_len_teacher[b];
        const float us = uss / user_len_school[b];
        const float agg = (seq + ut + us) * (1.0f / 3.0f);
        hvec[t]      = user_table[user_idx[b]*DD + t];
        hvec[DD + t] = agg;
    }
    __syncthreads();
    if (t < DD) {
        float a1 = g1b[t];
        #pragma unroll
        for (int k = 0; k < 2*DD; k++) a1 = fmaf(hvec[k], g1w[k*DD + t], a1);
        hid[t] = fmaxf(a1, 0.f);
    }
    __syncthreads();
    if (t < DD) {
        float a2 = g2b[t];
        #pragma unroll
        for (int k = 0; k < DD; k++) a2 = fmaf(hid[k], g2w[k*DD + t], a2);
        uf[t] = a2;
    }
    __syncthreads();

    // ---------------- epilogue: out[b,c] = dot(user_final, course_emb) ----------
    for (int c = t; c < NCC; c += 256) {
        const int ci = course_set[b*NCC + c];
        const float* ce = &course_table[ci*DD];
        float s = 0.f;
        #pragma unroll
        for (int g = 0; g < 4; g++) {
            const float4 cv = *(const float4*)&ce[g*4];
            const float4 uv = *(const float4*)&uf[g*4];
            s += cv.x*uv.x + cv.y*uv.y + cv.z*uv.z + cv.w*uv.w;
        }
        out[b*NCC + c] = s;
    }
}

extern "C" void kernel_launch(void* const* d_in, const int* in_sizes, int n_in,
                              void* d_out, int out_size, void* d_ws, size_t ws_size,
                              hipStream_t stream) {
    const int*   user_idx         = (const int*)  d_in[0];
    const int*   user_sequence    = (const int*)  d_in[1];
    const int*   user_teachers    = (const int*)  d_in[2];
    const int*   user_school      = (const int*)  d_in[3];
    const float* user_len_teacher = (const float*)d_in[5];
    const float* user_len_school  = (const float*)d_in[6];
    const int*   course_set       = (const int*)  d_in[7];
    const float* user_table       = (const float*)d_in[13];
    const float* course_table     = (const float*)d_in[14];
    const float* teacher_table    = (const float*)d_in[15];
    const float* school_table     = (const float*)d_in[16];
    const float* Qw  = (const float*)d_in[17];
    const float* Qb  = (const float*)d_in[18];
    const float* Kw  = (const float*)d_in[19];
    const float* Kb  = (const float*)d_in[20];
    const float* g1w = (const float*)d_in[21];
    const float* g1b = (const float*)d_in[22];
    const float* g2w = (const float*)d_in[23];
    const float* g2b = (const float*)d_in[24];

    float* outp = (float*)d_out;

    hipLaunchKernelGGL(hin_kernel, dim3(NBATCH), dim3(256), 0, stream,
                       user_idx, user_sequence, user_teachers, user_school,
                       user_len_teacher, user_len_school, course_set,
                       user_table, course_table, teacher_table, school_table,
                       Qw, Qb, Kw, Kb, g1w, g1b, g2w, g2b, outp);
}

// Round 4
// 26.103 us; speedup vs baseline: 2.8541x; 1.2396x over previous
//
#include <hip/hip_runtime.h>
#include <hip/hip_bf16.h>

#define NBATCH 1024
#define LSEQ   200
#define DD     16
#define LTT    10
#define LSCH   5
#define NCC    100

#define XT_S   232   // xt [16][232]: x^T [d][l], cols 200..207 zeroed
#define QB_S   24    // qb [208][24]: Q row-major [l][p]
#define KT_S   24    // kt [208][24]: Kflat rows [j][p^swz], rows 200..207 zeroed
#define WT_S   40    // wqt/wkt [16][40]: W^T [n][k], k 16..31 zeroed

typedef __bf16 bf16_8 __attribute__((ext_vector_type(8)));
typedef __bf16 bf16_4 __attribute__((ext_vector_type(4)));
typedef float  f32x4  __attribute__((ext_vector_type(4)));
typedef short  short4v __attribute__((ext_vector_type(4)));
typedef unsigned int uint2v __attribute__((ext_vector_type(2)));

__device__ __forceinline__ int kswz(int j) { return ((j >> 3) ^ (j >> 6)) & 1; }

__global__ __launch_bounds__(256, 4) void hin_kernel(
    const int*   __restrict__ user_idx,
    const int*   __restrict__ user_sequence,
    const int*   __restrict__ user_teachers,
    const int*   __restrict__ user_school,
    const float* __restrict__ user_len_teacher,
    const float* __restrict__ user_len_school,
    const int*   __restrict__ course_set,
    const float* __restrict__ user_table,
    const float* __restrict__ course_table,
    const float* __restrict__ teacher_table,
    const float* __restrict__ school_table,
    const float* __restrict__ Qw, const float* __restrict__ Qb,
    const float* __restrict__ Kw, const float* __restrict__ Kb,
    const float* __restrict__ g1w, const float* __restrict__ g1b,
    const float* __restrict__ g2w, const float* __restrict__ g2b,
    float*       __restrict__ out)
{
    __shared__ __align__(16) __bf16 xt[DD * XT_S];
    __shared__ __align__(16) __bf16 qb[208 * QB_S];
    __shared__ __align__(16) __bf16 kt[208 * KT_S];
    __shared__ __align__(16) __bf16 wqt[DD * WT_S], wkt[DD * WT_S];
    __shared__ float bQv[DD], bKv[DD];
    __shared__ float red[4][DD];
    __shared__ float hvec[2*DD], hid[DD], uf[DD];
    __shared__ float gst[800];       // g1w(512) | g1b(16) | g2w(256) | g2b(16)
    __shared__ float rows_pre[256];  // ue(16) | ut(160) | us(80)
    __shared__ float lens[2];
    __shared__ int   csets[NCC];

    const int b    = blockIdx.x;
    const int t    = threadIdx.x;
    const int w    = t >> 6;
    const int lane = t & 63;
    const int grp  = lane >> 4;
    const int li   = lane & 15;

    // ============ phase 0: stage everything global (issue loads early) =========
    {
        const int k = t >> 4, n = t & 15;
        wqt[n*WT_S + k]      = (__bf16)Qw[k*DD + n];
        wkt[n*WT_S + k]      = (__bf16)Kw[k*DD + n];
        wqt[n*WT_S + 16 + k] = (__bf16)0.f;
        wkt[n*WT_S + 16 + k] = (__bf16)0.f;
    }
    if (t < DD) { bQv[t] = Qb[t]; bKv[t] = Kb[t]; }
    if (t < 128)  // xt cols 200..207 zero
        xt[(t >> 3)*XT_S + 200 + (t & 7)] = (__bf16)0.f;
    else {        // kt rows 200..207 (cols 0..15) zero
        const int i = t - 128;
        kt[(200 + (i >> 4))*KT_S + (i & 15)] = (__bf16)0.f;
    }
    for (int i = t; i < 800; i += 256) {
        float v;
        if      (i < 512) v = g1w[i];
        else if (i < 528) v = g1b[i - 512];
        else if (i < 784) v = g2w[i - 528];
        else              v = g2b[i - 784];
        gst[i] = v;
    }
    {   // phase-4 gather rows
        if (t < 16)       rows_pre[t] = user_table[user_idx[b]*DD + t];
        else if (t < 176) { const int i = t - 16;
            rows_pre[t] = teacher_table[user_teachers[b*LTT + (i >> 4)]*DD + (i & 15)]; }
        else              { const int i = t - 176;
            rows_pre[t] = school_table[user_school[b*LSCH + (i >> 4)]*DD + (i & 15)]; }
    }
    if (t == 0) { lens[0] = user_len_teacher[b]; lens[1] = user_len_school[b]; }
    if (t < NCC) csets[t] = course_set[b*NCC + t];

    // ============ phase 1: gather x -> xt (transposed bf16) ====================
    for (int e = t; e < 800; e += 256) {
        const int l = e >> 2, dq = e & 3;
        const int idx = user_sequence[b*LSEQ + l];
        const float4 v = *(const float4*)&course_table[idx*DD + dq*4];
        xt[(dq*4+0)*XT_S + l] = (__bf16)v.x;
        xt[(dq*4+1)*XT_S + l] = (__bf16)v.y;
        xt[(dq*4+2)*XT_S + l] = (__bf16)v.z;
        xt[(dq*4+3)*XT_S + l] = (__bf16)v.w;
    }
    __syncthreads();

    bf16_8 zero8;
    #pragma unroll
    for (int i = 0; i < 8; i++) zero8[i] = (__bf16)0.f;

    // ============ phase 2: Q,K via MFMA -> qb (rows), kt (reshape scatter) =====
    {
        float qbias[4];
        #pragma unroll
        for (int r = 0; r < 4; r++) qbias[r] = bQv[grp*4 + r];
        const float kbias = bKv[li];
        const bf16_8 wq = *(const bf16_8*)&wqt[li*WT_S + grp*8];
        const bf16_8 wk = *(const bf16_8*)&wkt[li*WT_S + grp*8];
        for (int mt = w; mt < 13; mt += 4) {
            const int l0 = mt * 16;
            bf16_8 xf = zero8;
            if (grp < 2) {
                #pragma unroll
                for (int e = 0; e < 8; e++)
                    xf[e] = xt[(grp*8 + e)*XT_S + l0 + li];
            }
            f32x4 zc = {0.f, 0.f, 0.f, 0.f};
            // Q^T = Qw^T * x^T : lane -> Q[l0+li][grp*4+r]
            f32x4 qv = __builtin_amdgcn_mfma_f32_16x16x32_bf16(wq, xf, zc, 0, 0, 0);
            // K    = x * Kw    : lane -> K[l0+grp*4+r][li]
            f32x4 kv = __builtin_amdgcn_mfma_f32_16x16x32_bf16(xf, wk, zc, 0, 0, 0);
            bf16_4 qpk;
            #pragma unroll
            for (int r = 0; r < 4; r++)
                qpk[r] = (__bf16)fmaxf(qv[r] + qbias[r], 0.f);
            *(bf16_4*)&qb[(l0 + li)*QB_S + grp*4] = qpk;
            #pragma unroll
            for (int r = 0; r < 4; r++) {
                const int lrow = l0 + grp*4 + r;
                if (lrow < LSEQ) {
                    const float val = fmaxf(kv[r] + kbias, 0.f);
                    const int f = lrow*DD + li;       // flat idx, contiguous in li
                    const int p = f / 200;
                    const int j = f - p*200;
                    kt[j*KT_S + (p ^ (kswz(j) << 3))] = (__bf16)val;
                }
            }
        }
    }
    __syncthreads();

    // ============ phase 3: attention, P stays in registers =====================
    float wsum = 0.f;
    for (int mt = w; mt < 13; mt += 4) {
        const int m0 = mt * 16;
        bf16_8 qf = zero8;
        if (grp < 2) qf = *(const bf16_8*)&qb[(m0 + li)*QB_S + grp*8];

        f32x4 accv = {0.f, 0.f, 0.f, 0.f};
        float ps = 0.f;

        for (int jt = 0; jt < 13; jt++) {
            bf16_8 kf = zero8;
            if (grp < 2) {
                const int jr = jt*16 + li;
                kf = *(const bf16_8*)&kt[jr*KT_S + ((grp ^ kswz(jr)) << 3)];
            }
            f32x4 zc = {0.f, 0.f, 0.f, 0.f};
            // S^T-mfma: lane -> S[m0+li][jt*16+grp*4+r]
            f32x4 s = __builtin_amdgcn_mfma_f32_16x16x32_bf16(kf, qf, zc, 0, 0, 0);
            bf16_4 pa;
            #pragma unroll
            for (int r = 0; r < 4; r++) {
                float pv = __expf(s[r] * 0.25f);
                if (jt == 12 && grp >= 2) pv = 0.f;            // cols 200..207
                if (jt == mt && li == grp*4 + r) pv = 1.0f;    // diagonal
                ps += pv;
                pa[r] = (__bf16)pv;
            }
            // PV K=16 mfma: A = P-frag (in regs!), B = x rows from xt
            const bf16_4 xb = *(const bf16_4*)&xt[li*XT_S + jt*16 + grp*4];
#if __has_builtin(__builtin_amdgcn_mfma_f32_16x16x16bf16_1k)
            accv = __builtin_amdgcn_mfma_f32_16x16x16bf16_1k(
                __builtin_bit_cast(short4v, pa),
                __builtin_bit_cast(short4v, xb), accv, 0, 0, 0);
#else
            {
                uint2v pau = __builtin_bit_cast(uint2v, pa);
                uint2v xbu = __builtin_bit_cast(uint2v, xb);
                asm("v_mfma_f32_16x16x16_bf16 %0, %1, %2, %0"
                    : "+v"(accv) : "v"(pau), "v"(xbu));
            }
#endif
        }

        // row-total of P over all cols: reduce ps across grp (same li = same row)
        float tot = ps;
        tot += __shfl_xor(tot, 16);
        tot += __shfl_xor(tot, 32);
        // accv[r] = O[m0+grp*4+r][d=li]; fetch that row's denominator
        #pragma unroll
        for (int r = 0; r < 4; r++) {
            const int grow = m0 + grp*4 + r;
            const float dsum = __shfl(tot, grp*4 + r);
            const float a = accv[r] * __builtin_amdgcn_rcpf(dsum);
            wsum += (grow < LSEQ) ? a : 0.f;
        }
    }
    wsum += __shfl_xor(wsum, 16);
    wsum += __shfl_xor(wsum, 32);
    if (lane < DD) red[w][lane] = wsum;
    __syncthreads();

    // ============ phase 4: user vector + MLP (all from LDS) ====================
    if (t < DD) {
        const float seq = (red[0][t] + red[1][t] + red[2][t] + red[3][t]) * (1.0f / LSEQ);
        float uts = 0.f;
        #pragma unroll
        for (int i = 0; i < LTT; i++)  uts += rows_pre[16 + i*16 + t];
        float uss = 0.f;
        #pragma unroll
        for (int i = 0; i < LSCH; i++) uss += rows_pre[176 + i*16 + t];
        const float agg = (seq + uts / lens[0] + uss / lens[1]) * (1.0f / 3.0f);
        hvec[t]      = rows_pre[t];
        hvec[DD + t] = agg;
    }
    __syncthreads();
    if (t < DD) {
        float a1 = gst[512 + t];
        #pragma unroll
        for (int k = 0; k < 2*DD; k++) a1 = fmaf(hvec[k], gst[k*DD + t], a1);
        hid[t] = fmaxf(a1, 0.f);
    }
    __syncthreads();
    if (t < DD) {
        float a2 = gst[784 + t];
        #pragma unroll
        for (int k = 0; k < DD; k++) a2 = fmaf(hid[k], gst[528 + k*DD + t], a2);
        uf[t] = a2;
    }
    __syncthreads();

    // ============ epilogue: out[b,c] = dot(user_final, course_emb) =============
    if (t < NCC) {
        const int ci = csets[t];
        const float* ce = &course_table[ci*DD];
        float s = 0.f;
        #pragma unroll
        for (int g = 0; g < 4; g++) {
            const float4 cv = *(const float4*)&ce[g*4];
            const float4 uv = *(const float4*)&uf[g*4];
            s += cv.x*uv.x + cv.y*uv.y + cv.z*uv.z + cv.w*uv.w;
        }
        out[b*NCC + t] = s;
    }
}

extern "C" void kernel_launch(void* const* d_in, const int* in_sizes, int n_in,
                              void* d_out, int out_size, void* d_ws, size_t ws_size,
                              hipStream_t stream) {
    const int*   user_idx         = (const int*)  d_in[0];
    const int*   user_sequence    = (const int*)  d_in[1];
    const int*   user_teachers    = (const int*)  d_in[2];
    const int*   user_school      = (const int*)  d_in[3];
    const float* user_len_teacher = (const float*)d_in[5];
    const float* user_len_school  = (const float*)d_in[6];
    const int*   course_set       = (const int*)  d_in[7];
    const float* user_table       = (const float*)d_in[13];
    const float* course_table     = (const float*)d_in[14];
    const float* teacher_table    = (const float*)d_in[15];
    const float* school_table     = (const float*)d_in[16];
    const float* Qw  = (const float*)d_in[17];
    const float* Qb  = (const float*)d_in[18];
    const float* Kw  = (const float*)d_in[19];
    const float* Kb  = (const float*)d_in[20];
    const float* g1w = (const float*)d_in[21];
    const float* g1b = (const float*)d_in[22];
    const float* g2w = (const float*)d_in[23];
    const float* g2b = (const float*)d_in[24];

    float* outp = (float*)d_out;

    hipLaunchKernelGGL(hin_kernel, dim3(NBATCH), dim3(256), 0, stream,
                       user_idx, user_sequence, user_teachers, user_school,
                       user_len_teacher, user_len_school, course_set,
                       user_table, course_table, teacher_table, school_table,
                       Qw, Qb, Kw, Kb, g1w, g1b, g2w, g2b, outp);
}

// Round 6
// 23.539 us; speedup vs baseline: 3.1649x; 1.1089x over previous
//
#include <hip/hip_runtime.h>
#include <hip/hip_bf16.h>

#define NBATCH 1024
#define LSEQ   200
#define DD     16
#define LTT    10
#define LSCH   5
#define NCC    100

#define XT_S   232   // xt [16][232]: x^T [d][l], cols 200..207 zeroed
#define QB_S   24    // qb [208][24]: Q row-major [l][p] (pre-scaled by 0.25*log2e)
#define KT_S   24    // kt [208][24]: Kflat rows [j][p^swz], rows 200..207 zeroed
#define WT_S   20    // wqt/wkt [16][20]: W^T [n][k]

#define QSCALE 0.3606737602f   // 0.25 * log2(e)

typedef __bf16 bf16_4 __attribute__((ext_vector_type(4)));
typedef float  f32x4  __attribute__((ext_vector_type(4)));
typedef short  short4v __attribute__((ext_vector_type(4)));
typedef unsigned int uint2v __attribute__((ext_vector_type(2)));

__device__ __forceinline__ int kswz(int j) { return ((j >> 3) ^ (j >> 6)) & 1; }

__device__ __forceinline__ f32x4 mfma16(bf16_4 a, bf16_4 b, f32x4 c) {
#if __has_builtin(__builtin_amdgcn_mfma_f32_16x16x16bf16_1k)
    return __builtin_amdgcn_mfma_f32_16x16x16bf16_1k(
        __builtin_bit_cast(short4v, a), __builtin_bit_cast(short4v, b), c, 0, 0, 0);
#else
    uint2v au = __builtin_bit_cast(uint2v, a);
    uint2v bu = __builtin_bit_cast(uint2v, b);
    asm("v_mfma_f32_16x16x16_bf16 %0, %1, %2, %0" : "+v"(c) : "v"(au), "v"(bu));
    return c;
#endif
}

__global__ __launch_bounds__(256, 4) void hin_kernel(
    const int*   __restrict__ user_idx,
    const int*   __restrict__ user_sequence,
    const int*   __restrict__ user_teachers,
    const int*   __restrict__ user_school,
    const float* __restrict__ user_len_teacher,
    const float* __restrict__ user_len_school,
    const int*   __restrict__ course_set,
    const float* __restrict__ user_table,
    const float* __restrict__ course_table,
    const float* __restrict__ teacher_table,
    const float* __restrict__ school_table,
    const float* __restrict__ Qw, const float* __restrict__ Qb,
    const float* __restrict__ Kw, const float* __restrict__ Kb,
    const float* __restrict__ g1w, const float* __restrict__ g1b,
    const float* __restrict__ g2w, const float* __restrict__ g2b,
    float*       __restrict__ out)
{
    __shared__ __align__(16) __bf16 xt[DD * XT_S];
    __shared__ __align__(16) __bf16 qb[208 * QB_S];
    __shared__ __align__(16) __bf16 kt[208 * KT_S];
    __shared__ __align__(16) __bf16 wqt[DD * WT_S], wkt[DD * WT_S];
    __shared__ float bQv[DD], bKv[DD];
    __shared__ float red[4][DD];
    __shared__ float uf[DD];
    __shared__ float gst[800];       // g1w(512) | g1b(16) | g2w(256) | g2b(16)
    __shared__ float rows_pre[256];  // ue(16) | ut(160) | us(80)
    __shared__ float lens[2];
    __shared__ int   csets[NCC];

    const int b    = blockIdx.x;
    const int t    = threadIdx.x;
    const int w    = t >> 6;
    const int lane = t & 63;
    const int grp  = lane >> 4;
    const int li   = lane & 15;

    // ============ phase 0: stage all global data ==============================
    {
        const int k = t >> 4, n = t & 15;
        wqt[n*WT_S + k] = (__bf16)Qw[k*DD + n];
        wkt[n*WT_S + k] = (__bf16)Kw[k*DD + n];
    }
    if (t < DD) { bQv[t] = Qb[t]; bKv[t] = Kb[t]; }
    if (t < 128)  // xt cols 200..207 zero
        xt[(t >> 3)*XT_S + 200 + (t & 7)] = (__bf16)0.f;
    else {        // kt rows 200..207 cols 0..15 zero
        const int i = t - 128;
        kt[(200 + (i >> 4))*KT_S + (i & 15)] = (__bf16)0.f;
    }
    for (int i = t; i < 800; i += 256) {
        float v;
        if      (i < 512) v = g1w[i];
        else if (i < 528) v = g1b[i - 512];
        else if (i < 784) v = g2w[i - 528];
        else              v = g2b[i - 784];
        gst[i] = v;
    }
    if (t < 16)       rows_pre[t] = user_table[user_idx[b]*DD + t];
    else if (t < 176) { const int i = t - 16;
        rows_pre[t] = teacher_table[user_teachers[b*LTT + (i >> 4)]*DD + (i & 15)]; }
    else if (t < 256) { const int i = t - 176;
        rows_pre[t] = school_table[user_school[b*LSCH + (i >> 4)]*DD + (i & 15)]; }
    if (t == 0) { lens[0] = user_len_teacher[b]; lens[1] = user_len_school[b]; }
    if (t < NCC) csets[t] = course_set[b*NCC + t];

    // ============ phase 1: gather x -> xt (transposed bf16) ====================
    for (int e = t; e < 800; e += 256) {
        const int l = e >> 2, dq = e & 3;
        const int idx = user_sequence[b*LSEQ + l];
        const float4 v = *(const float4*)&course_table[idx*DD + dq*4];
        xt[(dq*4+0)*XT_S + l] = (__bf16)v.x;
        xt[(dq*4+1)*XT_S + l] = (__bf16)v.y;
        xt[(dq*4+2)*XT_S + l] = (__bf16)v.z;
        xt[(dq*4+3)*XT_S + l] = (__bf16)v.w;
    }
    __syncthreads();

    // ============ phase 2: Q,K via K=16 MFMA -> qb, kt =========================
    {
        float qbias[4];
        #pragma unroll
        for (int r = 0; r < 4; r++) qbias[r] = bQv[grp*4 + r];
        const float kbias = bKv[li];
        const bf16_4 wq = *(const bf16_4*)&wqt[li*WT_S + grp*4];
        const bf16_4 wk = *(const bf16_4*)&wkt[li*WT_S + grp*4];
        for (int mt = w; mt < 13; mt += 4) {
            const int l0 = mt * 16;
            bf16_4 xf;
            #pragma unroll
            for (int e = 0; e < 4; e++)
                xf[e] = xt[(grp*4 + e)*XT_S + l0 + li];
            const f32x4 zc = {0.f, 0.f, 0.f, 0.f};
            // Q^T = Qw^T * x^T : lane -> Q[l0+li][grp*4+r]
            f32x4 qv = mfma16(wq, xf, zc);
            // K    = x * Kw    : lane -> K[l0+grp*4+r][li]
            f32x4 kv = mfma16(xf, wk, zc);
            bf16_4 qpk;
            #pragma unroll
            for (int r = 0; r < 4; r++)
                qpk[r] = (__bf16)(QSCALE * fmaxf(qv[r] + qbias[r], 0.f));
            *(bf16_4*)&qb[(l0 + li)*QB_S + grp*4] = qpk;
            #pragma unroll
            for (int r = 0; r < 4; r++) {
                const int lrow = l0 + grp*4 + r;
                if (lrow < LSEQ) {
                    const float val = fmaxf(kv[r] + kbias, 0.f);
                    const int f = lrow*DD + li;
                    const int p = f / 200;
                    const int j = f - p*200;
                    kt[j*KT_S + (p ^ (kswz(j) << 3))] = (__bf16)val;
                }
            }
        }
    }
    __syncthreads();

    // ============ phase 3: attention, all K=16 MFMA, P in registers ============
    float wsum = 0.f;
    const int dr = li - grp*4;   // reg index hit by diagonal for this lane (or <0/>3)

    for (int mt = w; mt < 13; mt += 4) {
        const int m0 = mt * 16;
        const bf16_4 qf = *(const bf16_4*)&qb[(m0 + li)*QB_S + grp*4];

        f32x4 acc0 = {0.f, 0.f, 0.f, 0.f};
        f32x4 acc1 = {0.f, 0.f, 0.f, 0.f};
        f32x4 psv  = {0.f, 0.f, 0.f, 0.f};

        #pragma unroll
        for (int jt = 0; jt < 13; jt++) {
            const int jr = jt*16 + li;
            const bf16_4 kf = *(const bf16_4*)&kt[jr*KT_S + ((grp*4) ^ (kswz(jr) << 3))];
            const f32x4 zc = {0.f, 0.f, 0.f, 0.f};
            // lane -> S[m0+li][jt*16+grp*4+r], pre-scaled so p = exp2(s)
            f32x4 s = mfma16(kf, qf, zc);
            bf16_4 pa;
            #pragma unroll
            for (int r = 0; r < 4; r++) {
                float pv = __builtin_amdgcn_exp2f(s[r]);
                if (jt == 12 && grp >= 2) pv = 0.f;     // cols 200..207
                if (jt == mt && dr == r)  pv = 1.0f;    // diagonal
                psv[r] += pv;
                pa[r] = (__bf16)pv;
            }
            const bf16_4 xb = *(const bf16_4*)&xt[li*XT_S + jt*16 + grp*4];
            if (jt & 1) acc1 = mfma16(pa, xb, acc1);
            else        acc0 = mfma16(pa, xb, acc0);
        }

        // row-total of P: lane's partial covers its grp-quarter of cols
        float tot = (psv[0] + psv[1]) + (psv[2] + psv[3]);
        tot += __shfl_xor(tot, 16);
        tot += __shfl_xor(tot, 32);
        #pragma unroll
        for (int r = 0; r < 4; r++) {
            const int grow = m0 + grp*4 + r;
            const float dsum = __shfl(tot, grp*4 + r);
            const float a = (acc0[r] + acc1[r]) * __builtin_amdgcn_rcpf(dsum);
            wsum += (grow < LSEQ) ? a : 0.f;
        }
    }
    wsum += __shfl_xor(wsum, 16);
    wsum += __shfl_xor(wsum, 32);
    if (lane < DD) red[w][lane] = wsum;
    __syncthreads();

    // ============ phase 4: MLP in wave 0 via shuffles ==========================
    if (w == 0) {
        const float ue  = rows_pre[li];
        const float seq = (red[0][li] + red[1][li] + red[2][li] + red[3][li]) * (1.0f / LSEQ);
        float uts = 0.f;
        #pragma unroll
        for (int i = 0; i < LTT; i++)  uts += rows_pre[16 + i*16 + li];
        float uss = 0.f;
        #pragma unroll
        for (int i = 0; i < LSCH; i++) uss += rows_pre[176 + i*16 + li];
        const float agg = (seq + uts / lens[0] + uss / lens[1]) * (1.0f / 3.0f);
        float a1 = gst[512 + li];
        #pragma unroll
        for (int k = 0; k < 16; k++) a1 = fmaf(__shfl(ue,  k), gst[k*DD + li], a1);
        #pragma unroll
        for (int k = 0; k < 16; k++) a1 = fmaf(__shfl(agg, k), gst[(16 + k)*DD + li], a1);
        const float hidv = fmaxf(a1, 0.f);
        float a2 = gst[784 + li];
        #pragma unroll
        for (int k = 0; k < 16; k++) a2 = fmaf(__shfl(hidv, k), gst[528 + k*DD + li], a2);
        if (lane < DD) uf[lane] = a2;
    }
    __syncthreads();

    // ============ epilogue: out[b,c] = dot(user_final, course_emb) =============
    if (t < NCC) {
        const int ci = csets[t];
        const float* ce = &course_table[ci*DD];
        float s = 0.f;
        #pragma unroll
        for (int g = 0; g < 4; g++) {
            const float4 cv = *(const float4*)&ce[g*4];
            const float4 uv = *(const float4*)&uf[g*4];
            s += cv.x*uv.x + cv.y*uv.y + cv.z*uv.z + cv.w*uv.w;
        }
        out[b*NCC + t] = s;
    }
}

extern "C" void kernel_launch(void* const* d_in, const int* in_sizes, int n_in,
                              void* d_out, int out_size, void* d_ws, size_t ws_size,
                              hipStream_t stream) {
    const int*   user_idx         = (const int*)  d_in[0];
    const int*   user_sequence    = (const int*)  d_in[1];
    const int*   user_teachers    = (const int*)  d_in[2];
    const int*   user_school      = (const int*)  d_in[3];
    const float* user_len_teacher = (const float*)d_in[5];
    const float* user_len_school  = (const float*)d_in[6];
    const int*   course_set       = (const int*)  d_in[7];
    const float* user_table       = (const float*)d_in[13];
    const float* course_table     = (const float*)d_in[14];
    const float* teacher_table    = (const float*)d_in[15];
    const float* school_table     = (const float*)d_in[16];
    const float* Qw  = (const float*)d_in[17];
    const float* Qb  = (const float*)d_in[18];
    const float* Kw  = (const float*)d_in[19];
    const float* Kb  = (const float*)d_in[20];
    const float* g1w = (const float*)d_in[21];
    const float* g1b = (const float*)d_in[22];
    const float* g2w = (const float*)d_in[23];
    const float* g2b = (const float*)d_in[24];

    float* outp = (float*)d_out;

    hipLaunchKernelGGL(hin_kernel, dim3(NBATCH), dim3(256), 0, stream,
                       user_idx, user_sequence, user_teachers, user_school,
                       user_len_teacher, user_len_school, course_set,
                       user_table, course_table, teacher_table, school_table,
                       Qw, Qb, Kw, Kb, g1w, g1b, g2w, g2b, outp);
}

// Round 7
// 21.705 us; speedup vs baseline: 3.4323x; 1.0845x over previous
//
#include <hip/hip_runtime.h>
#include <hip/hip_bf16.h>

#define NBATCH 1024
#define LSEQ   200
#define DD     16
#define LTT    10
#define LSCH   5
#define NCC    100

#define XT_S   232   // xt [16][232]: x^T [d][l], cols 200..207 zeroed
#define QB_S   24    // qb [208][24]: Q row-major [l][p] (pre-scaled by 0.25*log2e)
#define KT_S   24    // kt [208][24]: Kflat rows [j][p^swz], rows 200..207 zeroed
#define WT_S   20    // wqt/wkt [16][20]: W^T [n][k]

#define QSCALE 0.3606737602f   // 0.25 * log2(e)

typedef __bf16 bf16_4 __attribute__((ext_vector_type(4)));
typedef float  f32x4  __attribute__((ext_vector_type(4)));
typedef short  short4v __attribute__((ext_vector_type(4)));
typedef unsigned int uint2v __attribute__((ext_vector_type(2)));

__device__ __forceinline__ int kswz(int j) { return ((j >> 3) ^ (j >> 6)) & 1; }

__device__ __forceinline__ f32x4 mfma16(bf16_4 a, bf16_4 b, f32x4 c) {
#if __has_builtin(__builtin_amdgcn_mfma_f32_16x16x16bf16_1k)
    return __builtin_amdgcn_mfma_f32_16x16x16bf16_1k(
        __builtin_bit_cast(short4v, a), __builtin_bit_cast(short4v, b), c, 0, 0, 0);
#else
    uint2v au = __builtin_bit_cast(uint2v, a);
    uint2v bu = __builtin_bit_cast(uint2v, b);
    asm("v_mfma_f32_16x16x16_bf16 %0, %1, %2, %0" : "+v"(c) : "v"(au), "v"(bu));
    return c;
#endif
}

__global__ __launch_bounds__(256, 4) void hin_kernel(
    const int*   __restrict__ user_idx,
    const int*   __restrict__ user_sequence,
    const int*   __restrict__ user_teachers,
    const int*   __restrict__ user_school,
    const float* __restrict__ user_len_teacher,
    const float* __restrict__ user_len_school,
    const int*   __restrict__ course_set,
    const float* __restrict__ user_table,
    const float* __restrict__ course_table,
    const float* __restrict__ teacher_table,
    const float* __restrict__ school_table,
    const float* __restrict__ Qw, const float* __restrict__ Qb,
    const float* __restrict__ Kw, const float* __restrict__ Kb,
    const float* __restrict__ g1w, const float* __restrict__ g1b,
    const float* __restrict__ g2w, const float* __restrict__ g2b,
    float*       __restrict__ out)
{
    __shared__ __align__(16) __bf16 xt[DD * XT_S];
    __shared__ __align__(16) __bf16 qb[208 * QB_S];
    __shared__ __align__(16) __bf16 kt[208 * KT_S];
    __shared__ __align__(16) __bf16 wqt[DD * WT_S], wkt[DD * WT_S];
    __shared__ float bQv[DD], bKv[DD];
    __shared__ float red[4][DD];
    __shared__ __align__(16) float tot12t[64];   // [row q][wave] tile-12 denom partials
    __shared__ float uf[DD];
    __shared__ float gst[800];       // g1w(512) | g1b(16) | g2w(256) | g2b(16)
    __shared__ float rows_pre[256];  // ue(16) | ut(160) | us(80)
    __shared__ float lens[2];
    __shared__ int   csets[NCC];

    const int b    = blockIdx.x;
    const int t    = threadIdx.x;
    const int w    = t >> 6;
    const int lane = t & 63;
    const int grp  = lane >> 4;
    const int li   = lane & 15;

    // ============ phase 0: stage all global data ==============================
    {
        const int k = t >> 4, n = t & 15;
        wqt[n*WT_S + k] = (__bf16)Qw[k*DD + n];
        wkt[n*WT_S + k] = (__bf16)Kw[k*DD + n];
    }
    if (t < DD) { bQv[t] = Qb[t]; bKv[t] = Kb[t]; }
    if (t < 128)  // xt cols 200..207 zero
        xt[(t >> 3)*XT_S + 200 + (t & 7)] = (__bf16)0.f;
    else {        // kt rows 200..207 cols 0..15 zero
        const int i = t - 128;
        kt[(200 + (i >> 4))*KT_S + (i & 15)] = (__bf16)0.f;
    }
    for (int i = t; i < 800; i += 256) {
        float v;
        if      (i < 512) v = g1w[i];
        else if (i < 528) v = g1b[i - 512];
        else if (i < 784) v = g2w[i - 528];
        else              v = g2b[i - 784];
        gst[i] = v;
    }
    if (t < 16)       rows_pre[t] = user_table[user_idx[b]*DD + t];
    else if (t < 176) { const int i = t - 16;
        rows_pre[t] = teacher_table[user_teachers[b*LTT + (i >> 4)]*DD + (i & 15)]; }
    else if (t < 256) { const int i = t - 176;
        rows_pre[t] = school_table[user_school[b*LSCH + (i >> 4)]*DD + (i & 15)]; }
    if (t == 0) { lens[0] = user_len_teacher[b]; lens[1] = user_len_school[b]; }
    if (t < NCC) csets[t] = course_set[b*NCC + t];

    // ============ phase 1: gather x -> xt (transposed bf16) ====================
    for (int e = t; e < 800; e += 256) {
        const int l = e >> 2, dq = e & 3;
        const int idx = user_sequence[b*LSEQ + l];
        const float4 v = *(const float4*)&course_table[idx*DD + dq*4];
        xt[(dq*4+0)*XT_S + l] = (__bf16)v.x;
        xt[(dq*4+1)*XT_S + l] = (__bf16)v.y;
        xt[(dq*4+2)*XT_S + l] = (__bf16)v.z;
        xt[(dq*4+3)*XT_S + l] = (__bf16)v.w;
    }
    __syncthreads();

    // ============ phase 2: Q,K via K=16 MFMA -> qb, kt =========================
    {
        float qbias[4];
        #pragma unroll
        for (int r = 0; r < 4; r++) qbias[r] = bQv[grp*4 + r];
        const float kbias = bKv[li];
        const bf16_4 wq = *(const bf16_4*)&wqt[li*WT_S + grp*4];
        const bf16_4 wk = *(const bf16_4*)&wkt[li*WT_S + grp*4];
        for (int mt = w; mt < 13; mt += 4) {
            const int l0 = mt * 16;
            bf16_4 xf;
            #pragma unroll
            for (int e = 0; e < 4; e++)
                xf[e] = xt[(grp*4 + e)*XT_S + l0 + li];
            const f32x4 zc = {0.f, 0.f, 0.f, 0.f};
            // Q^T = Qw^T * x^T : lane -> Q[l0+li][grp*4+r]
            f32x4 qv = mfma16(wq, xf, zc);
            // K    = x * Kw    : lane -> K[l0+grp*4+r][li]
            f32x4 kv = mfma16(xf, wk, zc);
            bf16_4 qpk;
            #pragma unroll
            for (int r = 0; r < 4; r++)
                qpk[r] = (__bf16)(QSCALE * fmaxf(qv[r] + qbias[r], 0.f));
            *(bf16_4*)&qb[(l0 + li)*QB_S + grp*4] = qpk;
            #pragma unroll
            for (int r = 0; r < 4; r++) {
                const int lrow = l0 + grp*4 + r;
                if (lrow < LSEQ) {
                    const float val = fmaxf(kv[r] + kbias, 0.f);
                    const int f = lrow*DD + li;
                    const int p = f / 200;
                    const int j = f - p*200;
                    kt[j*KT_S + (p ^ (kswz(j) << 3))] = (__bf16)val;
                }
            }
        }
    }
    __syncthreads();

    // ============ phase 3: attention; kf/xb hoisted to registers ==============
    const int wu = __builtin_amdgcn_readfirstlane(w);   // scalar wave id
    const int dr = li - grp*4;

    // mt-invariant fragments: load ONCE per wave (52 VGPRs)
    bf16_4 kfr[13], xbr[13];
    #pragma unroll
    for (int jt = 0; jt < 13; jt++) {
        const int jr = jt*16 + li;
        kfr[jt] = *(const bf16_4*)&kt[jr*KT_S + ((grp*4) ^ (kswz(jr) << 3))];
        xbr[jt] = *(const bf16_4*)&xt[li*XT_S + jt*16 + grp*4];
    }

    float wsum = 0.f;

    // ---- main tiles: wave wu owns mt in {wu, wu+4, wu+8} (3 each) ----
    #pragma unroll
    for (int mi = 0; mi < 3; mi++) {
        const int mt = wu + mi*4;
        const int m0 = mt * 16;
        const bf16_4 qf = *(const bf16_4*)&qb[(m0 + li)*QB_S + grp*4];

        f32x4 acc0 = {0.f, 0.f, 0.f, 0.f};
        f32x4 acc1 = {0.f, 0.f, 0.f, 0.f};
        f32x4 psv  = {0.f, 0.f, 0.f, 0.f};

        #pragma unroll
        for (int jt = 0; jt < 13; jt++) {
            const f32x4 zc = {0.f, 0.f, 0.f, 0.f};
            f32x4 s = mfma16(kfr[jt], qf, zc);   // S[m0+li][jt*16+grp*4+r]
            bf16_4 pa;
            #pragma unroll
            for (int r = 0; r < 4; r++) {
                float pv = __builtin_amdgcn_exp2f(s[r]);
                if (jt == 12 && grp >= 2) pv = 0.f;     // cols 200..207 (static)
                if (jt == mt && dr == r)  pv = 1.0f;    // diagonal (scalar cmp)
                psv[r] += pv;
                pa[r] = (__bf16)pv;
            }
            if (jt & 1) acc1 = mfma16(pa, xbr[jt], acc1);
            else        acc0 = mfma16(pa, xbr[jt], acc0);
        }

        float tot = (psv[0] + psv[1]) + (psv[2] + psv[3]);
        tot += __shfl_xor(tot, 16);
        tot += __shfl_xor(tot, 32);
        #pragma unroll
        for (int r = 0; r < 4; r++) {
            const float dsum = __shfl(tot, grp*4 + r);
            wsum += (acc0[r] + acc1[r]) * __builtin_amdgcn_rcpf(dsum);
        }
    }

    // ---- tile 12 (rows 192..207): jt-split across waves 4/3/3/3 ----
    f32x4 acc12 = {0.f, 0.f, 0.f, 0.f};
    {
        const int jlo = (wu == 0) ? 0 : (3*wu + 1);
        const int jhi = 3*wu + 4;
        const bf16_4 qf = *(const bf16_4*)&qb[(192 + li)*QB_S + grp*4];
        f32x4 psv = {0.f, 0.f, 0.f, 0.f};
        #pragma unroll
        for (int jt = 0; jt < 13; jt++) {
            if (jt >= jlo && jt < jhi) {         // wave-uniform (scalar) guard
                const f32x4 zc = {0.f, 0.f, 0.f, 0.f};
                f32x4 s = mfma16(kfr[jt], qf, zc);
                bf16_4 pa;
                #pragma unroll
                for (int r = 0; r < 4; r++) {
                    float pv = __builtin_amdgcn_exp2f(s[r]);
                    if (jt == 12 && grp >= 2) pv = 0.f;   // cols 200..207
                    if (jt == 12 && dr == r)  pv = 1.0f;  // diagonal (mt==12)
                    psv[r] += pv;
                    pa[r] = (__bf16)pv;
                }
                acc12 = mfma16(pa, xbr[jt], acc12);
            }
        }
        float tot = (psv[0] + psv[1]) + (psv[2] + psv[3]);
        tot += __shfl_xor(tot, 16);
        tot += __shfl_xor(tot, 32);
        if (lane < 16) tot12t[li*4 + w] = tot;   // partial denom, row 192+li
    }
    __syncthreads();

    // combine tile-12: full denominator = sum of 4 wave partials
    #pragma unroll
    for (int r = 0; r < 4; r++) {
        const int q = grp*4 + r;                 // row 192+q
        const float4 p4 = *(const float4*)&tot12t[q*4];
        const float dsum = (p4.x + p4.y) + (p4.z + p4.w);
        const float a = acc12[r] * __builtin_amdgcn_rcpf(dsum);
        wsum += (192 + q < LSEQ) ? a : 0.f;
    }

    wsum += __shfl_xor(wsum, 16);
    wsum += __shfl_xor(wsum, 32);
    if (lane < DD) red[w][lane] = wsum;
    __syncthreads();

    // ============ phase 4: MLP in wave 0 via shuffles ==========================
    if (w == 0) {
        const float ue  = rows_pre[li];
        const float seq = (red[0][li] + red[1][li] + red[2][li] + red[3][li]) * (1.0f / LSEQ);
        float uts = 0.f;
        #pragma unroll
        for (int i = 0; i < LTT; i++)  uts += rows_pre[16 + i*16 + li];
        float uss = 0.f;
        #pragma unroll
        for (int i = 0; i < LSCH; i++) uss += rows_pre[176 + i*16 + li];
        const float agg = (seq + uts / lens[0] + uss / lens[1]) * (1.0f / 3.0f);
        float a1 = gst[512 + li];
        #pragma unroll
        for (int k = 0; k < 16; k++) a1 = fmaf(__shfl(ue,  k), gst[k*DD + li], a1);
        #pragma unroll
        for (int k = 0; k < 16; k++) a1 = fmaf(__shfl(agg, k), gst[(16 + k)*DD + li], a1);
        const float hidv = fmaxf(a1, 0.f);
        float a2 = gst[784 + li];
        #pragma unroll
        for (int k = 0; k < 16; k++) a2 = fmaf(__shfl(hidv, k), gst[528 + k*DD + li], a2);
        if (lane < DD) uf[lane] = a2;
    }
    __syncthreads();

    // ============ epilogue: out[b,c] = dot(user_final, course_emb) =============
    if (t < NCC) {
        const int ci = csets[t];
        const float* ce = &course_table[ci*DD];
        float s = 0.f;
        #pragma unroll
        for (int g = 0; g < 4; g++) {
            const float4 cv = *(const float4*)&ce[g*4];
            const float4 uv = *(const float4*)&uf[g*4];
            s += cv.x*uv.x + cv.y*uv.y + cv.z*uv.z + cv.w*uv.w;
        }
        out[b*NCC + t] = s;
    }
}

extern "C" void kernel_launch(void* const* d_in, const int* in_sizes, int n_in,
                              void* d_out, int out_size, void* d_ws, size_t ws_size,
                              hipStream_t stream) {
    const int*   user_idx         = (const int*)  d_in[0];
    const int*   user_sequence    = (const int*)  d_in[1];
    const int*   user_teachers    = (const int*)  d_in[2];
    const int*   user_school      = (const int*)  d_in[3];
    const float* user_len_teacher = (const float*)d_in[5];
    const float* user_len_school  = (const float*)d_in[6];
    const int*   course_set       = (const int*)  d_in[7];
    const float* user_table       = (const float*)d_in[13];
    const float* course_table     = (const float*)d_in[14];
    const float* teacher_table    = (const float*)d_in[15];
    const float* school_table     = (const float*)d_in[16];
    const float* Qw  = (const float*)d_in[17];
    const float* Qb  = (const float*)d_in[18];
    const float* Kw  = (const float*)d_in[19];
    const float* Kb  = (const float*)d_in[20];
    const float* g1w = (const float*)d_in[21];
    const float* g1b = (const float*)d_in[22];
    const float* g2w = (const float*)d_in[23];
    const float* g2b = (const float*)d_in[24];

    float* outp = (float*)d_out;

    hipLaunchKernelGGL(hin_kernel, dim3(NBATCH), dim3(256), 0, stream,
                       user_idx, user_sequence, user_teachers, user_school,
                       user_len_teacher, user_len_school, course_set,
                       user_table, course_table, teacher_table, school_table,
                       Qw, Qb, Kw, Kb, g1w, g1b, g2w, g2b, outp);
}

// Round 8
// 20.932 us; speedup vs baseline: 3.5591x; 1.0370x over previous
//
#include <hip/hip_runtime.h>
#include <hip/hip_bf16.h>

#define NBATCH 1024
#define LSEQ   200
#define DD     16
#define LTT    10
#define LSCH   5
#define NCC    100

#define XT_S   232   // xt [16][232]: x^T [d][l], cols 200..207 zeroed
#define QB_S   24    // qb [208][24]: Q row-major [l][p] (pre-scaled by 0.25*log2e)
#define KT_S   24    // kt [208][24]: Kflat rows [j][p^swz], rows 200..207 zeroed
#define WT_S   20    // wqt/wkt [16][20]: W^T [n][k]

#define QSCALE 0.3606737602f   // 0.25 * log2(e)

typedef __bf16 bf16_4 __attribute__((ext_vector_type(4)));
typedef float  f32x4  __attribute__((ext_vector_type(4)));
typedef short  short4v __attribute__((ext_vector_type(4)));
typedef unsigned int uint2v __attribute__((ext_vector_type(2)));

__device__ __forceinline__ int kswz(int j) { return ((j >> 3) ^ (j >> 6)) & 1; }

__device__ __forceinline__ f32x4 mfma16(bf16_4 a, bf16_4 b, f32x4 c) {
#if __has_builtin(__builtin_amdgcn_mfma_f32_16x16x16bf16_1k)
    return __builtin_amdgcn_mfma_f32_16x16x16bf16_1k(
        __builtin_bit_cast(short4v, a), __builtin_bit_cast(short4v, b), c, 0, 0, 0);
#else
    uint2v au = __builtin_bit_cast(uint2v, a);
    uint2v bu = __builtin_bit_cast(uint2v, b);
    asm("v_mfma_f32_16x16x16_bf16 %0, %1, %2, %0" : "+v"(c) : "v"(au), "v"(bu));
    return c;
#endif
}

__global__ __launch_bounds__(256, 4) void hin_kernel(
    const int*   __restrict__ user_idx,
    const int*   __restrict__ user_sequence,
    const int*   __restrict__ user_teachers,
    const int*   __restrict__ user_school,
    const float* __restrict__ user_len_teacher,
    const float* __restrict__ user_len_school,
    const int*   __restrict__ course_set,
    const float* __restrict__ user_table,
    const float* __restrict__ course_table,
    const float* __restrict__ teacher_table,
    const float* __restrict__ school_table,
    const float* __restrict__ Qw, const float* __restrict__ Qb,
    const float* __restrict__ Kw, const float* __restrict__ Kb,
    const float* __restrict__ g1w, const float* __restrict__ g1b,
    const float* __restrict__ g2w, const float* __restrict__ g2b,
    float*       __restrict__ out)
{
    __shared__ __align__(16) __bf16 xt[DD * XT_S];
    __shared__ __align__(16) __bf16 qb[208 * QB_S];
    __shared__ __align__(16) __bf16 kt[208 * KT_S];
    __shared__ __align__(16) __bf16 wqt[DD * WT_S], wkt[DD * WT_S];
    __shared__ float bQv[DD], bKv[DD];
    __shared__ float red[4][DD];
    __shared__ __align__(16) float tot12t[64];   // [row q][wave] tile-12 denom partials
    __shared__ float uf[DD];
    __shared__ float gst[800];       // g1w(512) | g1b(16) | g2w(256) | g2b(16)
    __shared__ float rows_pre[256];  // ue(16) | ut(160) | us(80)
    __shared__ float lens[2];

    const int b    = blockIdx.x;
    const int t    = threadIdx.x;
    const int w    = t >> 6;
    const int lane = t & 63;
    const int grp  = lane >> 4;
    const int li   = lane & 15;

    // ============ phase 0: stage all global data ==============================
    {
        const int k = t >> 4, n = t & 15;
        wqt[n*WT_S + k] = (__bf16)Qw[k*DD + n];
        wkt[n*WT_S + k] = (__bf16)Kw[k*DD + n];
    }
    if (t < DD) { bQv[t] = Qb[t]; bKv[t] = Kb[t]; }
    if (t < 128)  // xt cols 200..207 zero
        xt[(t >> 3)*XT_S + 200 + (t & 7)] = (__bf16)0.f;
    else {        // kt rows 200..207 cols 0..15 zero
        const int i = t - 128;
        kt[(200 + (i >> 4))*KT_S + (i & 15)] = (__bf16)0.f;
    }
    for (int i = t; i < 800; i += 256) {
        float v;
        if      (i < 512) v = g1w[i];
        else if (i < 528) v = g1b[i - 512];
        else if (i < 784) v = g2w[i - 528];
        else              v = g2b[i - 784];
        gst[i] = v;
    }
    if (t < 16)       rows_pre[t] = user_table[user_idx[b]*DD + t];
    else if (t < 176) { const int i = t - 16;
        rows_pre[t] = teacher_table[user_teachers[b*LTT + (i >> 4)]*DD + (i & 15)]; }
    else if (t < 256) { const int i = t - 176;
        rows_pre[t] = school_table[user_school[b*LSCH + (i >> 4)]*DD + (i & 15)]; }
    if (t == 0) { lens[0] = user_len_teacher[b]; lens[1] = user_len_school[b]; }

    // ============ phase 1: gather x -> xt (transposed bf16) ====================
    for (int e = t; e < 800; e += 256) {
        const int l = e >> 2, dq = e & 3;
        const int idx = user_sequence[b*LSEQ + l];
        const float4 v = *(const float4*)&course_table[idx*DD + dq*4];
        xt[(dq*4+0)*XT_S + l] = (__bf16)v.x;
        xt[(dq*4+1)*XT_S + l] = (__bf16)v.y;
        xt[(dq*4+2)*XT_S + l] = (__bf16)v.z;
        xt[(dq*4+3)*XT_S + l] = (__bf16)v.w;
    }
    __syncthreads();

    // ============ phase 2: Q,K via K=16 MFMA -> qb, kt =========================
    {
        float qbias[4];
        #pragma unroll
        for (int r = 0; r < 4; r++) qbias[r] = bQv[grp*4 + r];
        const float kbias = bKv[li];
        const bf16_4 wq = *(const bf16_4*)&wqt[li*WT_S + grp*4];
        const bf16_4 wk = *(const bf16_4*)&wkt[li*WT_S + grp*4];
        for (int mt = w; mt < 13; mt += 4) {
            const int l0 = mt * 16;
            bf16_4 xf;
            #pragma unroll
            for (int e = 0; e < 4; e++)
                xf[e] = xt[(grp*4 + e)*XT_S + l0 + li];
            const f32x4 zc = {0.f, 0.f, 0.f, 0.f};
            // Q^T = Qw^T * x^T : lane -> Q[l0+li][grp*4+r]
            f32x4 qv = mfma16(wq, xf, zc);
            // K    = x * Kw    : lane -> K[l0+grp*4+r][li]
            f32x4 kv = mfma16(xf, wk, zc);
            bf16_4 qpk;
            #pragma unroll
            for (int r = 0; r < 4; r++)
                qpk[r] = (__bf16)(QSCALE * fmaxf(qv[r] + qbias[r], 0.f));
            *(bf16_4*)&qb[(l0 + li)*QB_S + grp*4] = qpk;
            #pragma unroll
            for (int r = 0; r < 4; r++) {
                const int lrow = l0 + grp*4 + r;
                if (lrow < LSEQ) {
                    const float val = fmaxf(kv[r] + kbias, 0.f);
                    const int f = lrow*DD + li;
                    const int p = f / 200;
                    const int j = f - p*200;
                    kt[j*KT_S + (p ^ (kswz(j) << 3))] = (__bf16)val;
                }
            }
        }
    }
    __syncthreads();

    // ============ phase 3: attention; denominators via ones-MFMA ==============
    const int wu = __builtin_amdgcn_readfirstlane(w);   // scalar wave id
    const int dr = li - grp*4;

    bf16_4 onesb;
    #pragma unroll
    for (int i = 0; i < 4; i++) onesb[i] = (__bf16)1.0f;

    // mt-invariant fragments: load ONCE per wave
    bf16_4 kfr[13], xbr[13];
    #pragma unroll
    for (int jt = 0; jt < 13; jt++) {
        const int jr = jt*16 + li;
        kfr[jt] = *(const bf16_4*)&kt[jr*KT_S + ((grp*4) ^ (kswz(jr) << 3))];
        xbr[jt] = *(const bf16_4*)&xt[li*XT_S + jt*16 + grp*4];
    }

    float wsum = 0.f;

    // ---- main tiles: wave wu owns mt in {wu, wu+4, wu+8} (3 each) ----
    #pragma unroll
    for (int mi = 0; mi < 3; mi++) {
        const int mt = wu + mi*4;
        const int m0 = mt * 16;
        const bf16_4 qf = *(const bf16_4*)&qb[(m0 + li)*QB_S + grp*4];

        f32x4 acc0 = {0.f, 0.f, 0.f, 0.f};
        f32x4 acc1 = {0.f, 0.f, 0.f, 0.f};
        f32x4 accD = {0.f, 0.f, 0.f, 0.f};

        #pragma unroll
        for (int jt = 0; jt < 13; jt++) {
            const f32x4 zc = {0.f, 0.f, 0.f, 0.f};
            f32x4 s = mfma16(kfr[jt], qf, zc);   // S[m0+li][jt*16+grp*4+r]
            bf16_4 pa;
            #pragma unroll
            for (int r = 0; r < 4; r++) {
                float pv = __builtin_amdgcn_exp2f(s[r]);
                if (jt == 12 && grp >= 2) pv = 0.f;     // cols 200..207 (static)
                if (jt == mt && dr == r)  pv = 1.0f;    // diagonal (scalar cmp)
                pa[r] = (__bf16)pv;
            }
            accD = mfma16(pa, onesb, accD);            // row-sum of P, row m0+grp*4+r
            if (jt & 1) acc1 = mfma16(pa, xbr[jt], acc1);
            else        acc0 = mfma16(pa, xbr[jt], acc0);
        }

        // accD[r] is the denominator of EXACTLY the row held in acc*[r] — no shuffles
        #pragma unroll
        for (int r = 0; r < 4; r++)
            wsum += (acc0[r] + acc1[r]) * __builtin_amdgcn_rcpf(accD[r]);
    }

    // ---- tile 12 (rows 192..207): jt-split across waves 4/3/3/3 ----
    f32x4 acc12 = {0.f, 0.f, 0.f, 0.f};
    {
        const int jlo = (wu == 0) ? 0 : (3*wu + 1);
        const int jhi = 3*wu + 4;
        const bf16_4 qf = *(const bf16_4*)&qb[(192 + li)*QB_S + grp*4];
        f32x4 accD = {0.f, 0.f, 0.f, 0.f};
        #pragma unroll
        for (int jt = 0; jt < 13; jt++) {
            if (jt >= jlo && jt < jhi) {         // wave-uniform (scalar) guard
                const f32x4 zc = {0.f, 0.f, 0.f, 0.f};
                f32x4 s = mfma16(kfr[jt], qf, zc);
                bf16_4 pa;
                #pragma unroll
                for (int r = 0; r < 4; r++) {
                    float pv = __builtin_amdgcn_exp2f(s[r]);
                    if (jt == 12 && grp >= 2) pv = 0.f;   // cols 200..207
                    if (jt == 12 && dr == r)  pv = 1.0f;  // diagonal (mt==12)
                    pa[r] = (__bf16)pv;
                }
                accD  = mfma16(pa, onesb, accD);
                acc12 = mfma16(pa, xbr[jt], acc12);
            }
        }
        if (li == 0) {                            // accD[r] uniform across li
            #pragma unroll
            for (int r = 0; r < 4; r++)
                tot12t[(grp*4 + r)*4 + w] = accD[r];
        }
    }
    __syncthreads();

    // combine tile-12: full denominator = sum of 4 wave partials
    #pragma unroll
    for (int r = 0; r < 4; r++) {
        const int q = grp*4 + r;                 // row 192+q
        const float4 p4 = *(const float4*)&tot12t[q*4];
        const float dsum = (p4.x + p4.y) + (p4.z + p4.w);
        const float a = acc12[r] * __builtin_amdgcn_rcpf(dsum);
        wsum += (192 + q < LSEQ) ? a : 0.f;
    }

    wsum += __shfl_xor(wsum, 16);
    wsum += __shfl_xor(wsum, 32);
    if (lane < DD) red[w][lane] = wsum;
    __syncthreads();

    // ============ epilogue prefetch: issue course-row loads under the MLP ======
    float4 ce0, ce1, ce2, ce3;
    if (t < NCC) {
        const int ci = course_set[b*NCC + t];
        const float* ce = &course_table[ci*DD];
        ce0 = *(const float4*)&ce[0];
        ce1 = *(const float4*)&ce[4];
        ce2 = *(const float4*)&ce[8];
        ce3 = *(const float4*)&ce[12];
    }

    // ============ phase 4: MLP in wave 0 via shuffles ==========================
    if (w == 0) {
        const float ue  = rows_pre[li];
        const float seq = (red[0][li] + red[1][li] + red[2][li] + red[3][li]) * (1.0f / LSEQ);
        float uts = 0.f;
        #pragma unroll
        for (int i = 0; i < LTT; i++)  uts += rows_pre[16 + i*16 + li];
        float uss = 0.f;
        #pragma unroll
        for (int i = 0; i < LSCH; i++) uss += rows_pre[176 + i*16 + li];
        const float agg = (seq + uts / lens[0] + uss / lens[1]) * (1.0f / 3.0f);
        float a1 = gst[512 + li];
        #pragma unroll
        for (int k = 0; k < 16; k++) a1 = fmaf(__shfl(ue,  k), gst[k*DD + li], a1);
        #pragma unroll
        for (int k = 0; k < 16; k++) a1 = fmaf(__shfl(agg, k), gst[(16 + k)*DD + li], a1);
        const float hidv = fmaxf(a1, 0.f);
        float a2 = gst[784 + li];
        #pragma unroll
        for (int k = 0; k < 16; k++) a2 = fmaf(__shfl(hidv, k), gst[528 + k*DD + li], a2);
        if (lane < DD) uf[lane] = a2;
    }
    __syncthreads();

    // ============ epilogue: dot with prefetched rows ===========================
    if (t < NCC) {
        const float4 u0 = *(const float4*)&uf[0];
        const float4 u1 = *(const float4*)&uf[4];
        const float4 u2 = *(const float4*)&uf[8];
        const float4 u3 = *(const float4*)&uf[12];
        float s = ce0.x*u0.x + ce0.y*u0.y + ce0.z*u0.z + ce0.w*u0.w;
        s      += ce1.x*u1.x + ce1.y*u1.y + ce1.z*u1.z + ce1.w*u1.w;
        s      += ce2.x*u2.x + ce2.y*u2.y + ce2.z*u2.z + ce2.w*u2.w;
        s      += ce3.x*u3.x + ce3.y*u3.y + ce3.z*u3.z + ce3.w*u3.w;
        out[b*NCC + t] = s;
    }
}

extern "C" void kernel_launch(void* const* d_in, const int* in_sizes, int n_in,
                              void* d_out, int out_size, void* d_ws, size_t ws_size,
                              hipStream_t stream) {
    const int*   user_idx         = (const int*)  d_in[0];
    const int*   user_sequence    = (const int*)  d_in[1];
    const int*   user_teachers    = (const int*)  d_in[2];
    const int*   user_school      = (const int*)  d_in[3];
    const float* user_len_teacher = (const float*)d_in[5];
    const float* user_len_school  = (const float*)d_in[6];
    const int*   course_set       = (const int*)  d_in[7];
    const float* user_table       = (const float*)d_in[13];
    const float* course_table     = (const float*)d_in[14];
    const float* teacher_table    = (const float*)d_in[15];
    const float* school_table     = (const float*)d_in[16];
    const float* Qw  = (const float*)d_in[17];
    const float* Qb  = (const float*)d_in[18];
    const float* Kw  = (const float*)d_in[19];
    const float* Kb  = (const float*)d_in[20];
    const float* g1w = (const float*)d_in[21];
    const float* g1b = (const float*)d_in[22];
    const float* g2w = (const float*)d_in[23];
    const float* g2b = (const float*)d_in[24];

    float* outp = (float*)d_out;

    hipLaunchKernelGGL(hin_kernel, dim3(NBATCH), dim3(256), 0, stream,
                       user_idx, user_sequence, user_teachers, user_school,
                       user_len_teacher, user_len_school, course_set,
                       user_table, course_table, teacher_table, school_table,
                       Qw, Qb, Kw, Kb, g1w, g1b, g2w, g2b, outp);
}

// Round 9
// 20.731 us; speedup vs baseline: 3.5935x; 1.0097x over previous
//
#include <hip/hip_runtime.h>
#include <hip/hip_bf16.h>

#define NBATCH 1024
#define LSEQ   200
#define DD     16
#define LTT    10
#define LSCH   5
#define NCC    100

#define XT_S   232   // xt [16][232]: x^T [d][l], cols 200..207 zeroed
#define KT_S   24    // kt [208][24]: Kflat rows [j][p^swz], rows 200..207 zeroed
#define WT_S   20    // wqt/wkt [16][20]: W^T [n][k]

#define QSCALE 0.3606737602f   // 0.25 * log2(e)

typedef __bf16 bf16_4 __attribute__((ext_vector_type(4)));
typedef float  f32x4  __attribute__((ext_vector_type(4)));
typedef short  short4v __attribute__((ext_vector_type(4)));
typedef unsigned int uint2v __attribute__((ext_vector_type(2)));

__device__ __forceinline__ int kswz(int j) { return ((j >> 3) ^ (j >> 6)) & 1; }

__device__ __forceinline__ f32x4 mfma16(bf16_4 a, bf16_4 b, f32x4 c) {
#if __has_builtin(__builtin_amdgcn_mfma_f32_16x16x16bf16_1k)
    return __builtin_amdgcn_mfma_f32_16x16x16bf16_1k(
        __builtin_bit_cast(short4v, a), __builtin_bit_cast(short4v, b), c, 0, 0, 0);
#else
    uint2v au = __builtin_bit_cast(uint2v, a);
    uint2v bu = __builtin_bit_cast(uint2v, b);
    asm("v_mfma_f32_16x16x16_bf16 %0, %1, %2, %0" : "+v"(c) : "v"(au), "v"(bu));
    return c;
#endif
}

__global__ __launch_bounds__(256, 4) void hin_kernel(
    const int*   __restrict__ user_idx,
    const int*   __restrict__ user_sequence,
    const int*   __restrict__ user_teachers,
    const int*   __restrict__ user_school,
    const float* __restrict__ user_len_teacher,
    const float* __restrict__ user_len_school,
    const int*   __restrict__ course_set,
    const float* __restrict__ user_table,
    const float* __restrict__ course_table,
    const float* __restrict__ teacher_table,
    const float* __restrict__ school_table,
    const float* __restrict__ Qw, const float* __restrict__ Qb,
    const float* __restrict__ Kw, const float* __restrict__ Kb,
    const float* __restrict__ g1w, const float* __restrict__ g1b,
    const float* __restrict__ g2w, const float* __restrict__ g2b,
    float*       __restrict__ out)
{
    __shared__ __align__(16) __bf16 xt[DD * XT_S];
    __shared__ __align__(16) __bf16 kt[208 * KT_S];
    __shared__ __align__(16) __bf16 wqt[DD * WT_S], wkt[DD * WT_S];
    __shared__ float bQv[DD], bKv[DD];
    __shared__ float red[4][DD];
    __shared__ __align__(16) float tot12t[64];   // [row q][wave] tile-12 denom partials
    __shared__ float uf[DD];
    __shared__ float gst[800];       // g1w(512) | g1b(16) | g2w(256) | g2b(16)
    __shared__ float rows_pre[256];  // ue(16) | ut(160) | us(80)
    __shared__ float lens[2];

    const int b    = blockIdx.x;
    const int t    = threadIdx.x;
    const int w    = t >> 6;
    const int lane = t & 63;
    const int grp  = lane >> 4;
    const int li   = lane & 15;

    // ============ phase 0: stage all global data ==============================
    {
        const int k = t >> 4, n = t & 15;
        wqt[n*WT_S + k] = (__bf16)Qw[k*DD + n];
        wkt[n*WT_S + k] = (__bf16)Kw[k*DD + n];
    }
    if (t < DD) { bQv[t] = Qb[t]; bKv[t] = Kb[t]; }
    if (t < 128)  // xt cols 200..207 zero
        xt[(t >> 3)*XT_S + 200 + (t & 7)] = (__bf16)0.f;
    else {        // kt rows 200..207 cols 0..15 zero
        const int i = t - 128;
        kt[(200 + (i >> 4))*KT_S + (i & 15)] = (__bf16)0.f;
    }
    for (int i = t; i < 800; i += 256) {
        float v;
        if      (i < 512) v = g1w[i];
        else if (i < 528) v = g1b[i - 512];
        else if (i < 784) v = g2w[i - 528];
        else              v = g2b[i - 784];
        gst[i] = v;
    }
    if (t < 16)       rows_pre[t] = user_table[user_idx[b]*DD + t];
    else if (t < 176) { const int i = t - 16;
        rows_pre[t] = teacher_table[user_teachers[b*LTT + (i >> 4)]*DD + (i & 15)]; }
    else if (t < 256) { const int i = t - 176;
        rows_pre[t] = school_table[user_school[b*LSCH + (i >> 4)]*DD + (i & 15)]; }
    if (t == 0) { lens[0] = user_len_teacher[b]; lens[1] = user_len_school[b]; }

    // ============ phase 1: gather x -> xt (transposed bf16) ====================
    for (int e = t; e < 800; e += 256) {
        const int l = e >> 2, dq = e & 3;
        const int idx = user_sequence[b*LSEQ + l];
        const float4 v = *(const float4*)&course_table[idx*DD + dq*4];
        xt[(dq*4+0)*XT_S + l] = (__bf16)v.x;
        xt[(dq*4+1)*XT_S + l] = (__bf16)v.y;
        xt[(dq*4+2)*XT_S + l] = (__bf16)v.z;
        xt[(dq*4+3)*XT_S + l] = (__bf16)v.w;
    }
    __syncthreads();

    const int wu = __builtin_amdgcn_readfirstlane(w);   // scalar wave id
    const int dr = li - grp*4;

    // ============ phase 2: Q,K via K=16 MFMA; Q stays in REGISTERS =============
    bf16_4 qf0, qf1, qf2, qf12;
    {
        float qbias[4];
        #pragma unroll
        for (int r = 0; r < 4; r++) qbias[r] = bQv[grp*4 + r];
        const float kbias = bKv[li];
        const bf16_4 wq = *(const bf16_4*)&wqt[li*WT_S + grp*4];
        const bf16_4 wk = *(const bf16_4*)&wkt[li*WT_S + grp*4];

        auto compute_qk = [&](int l0, bf16_4& qout, bool do_scatter) {
            bf16_4 xf;
            #pragma unroll
            for (int e = 0; e < 4; e++)
                xf[e] = xt[(grp*4 + e)*XT_S + l0 + li];
            const f32x4 zc = {0.f, 0.f, 0.f, 0.f};
            // Q^T = Qw^T * x^T : lane -> Q[l0+li][grp*4+r]  (B-frag layout!)
            f32x4 qv = mfma16(wq, xf, zc);
            // K    = x * Kw    : lane -> K[l0+grp*4+r][li]
            f32x4 kv = mfma16(xf, wk, zc);
            #pragma unroll
            for (int r = 0; r < 4; r++)
                qout[r] = (__bf16)(QSCALE * fmaxf(qv[r] + qbias[r], 0.f));
            if (do_scatter) {
                #pragma unroll
                for (int r = 0; r < 4; r++) {
                    const int lrow = l0 + grp*4 + r;
                    if (lrow < LSEQ) {
                        const float val = fmaxf(kv[r] + kbias, 0.f);
                        const int f = lrow*DD + li;
                        const int p = f / 200;
                        const int j = f - p*200;
                        kt[j*KT_S + (p ^ (kswz(j) << 3))] = (__bf16)val;
                    }
                }
            }
        };
        compute_qk(wu*16,       qf0, true);
        compute_qk((wu+4)*16,   qf1, true);
        compute_qk((wu+8)*16,   qf2, true);
        compute_qk(192,         qf12, wu == 0);   // all waves need tile-12 Q
    }
    __syncthreads();

    // ============ phase 3: attention, 4 tiles interleaved per jt (ILP) ========
    bf16_4 onesb;
    #pragma unroll
    for (int i = 0; i < 4; i++) onesb[i] = (__bf16)1.0f;

    // mt-invariant fragments: load ONCE per wave
    bf16_4 kfr[13], xbr[13];
    #pragma unroll
    for (int jt = 0; jt < 13; jt++) {
        const int jr = jt*16 + li;
        kfr[jt] = *(const bf16_4*)&kt[jr*KT_S + ((grp*4) ^ (kswz(jr) << 3))];
        xbr[jt] = *(const bf16_4*)&xt[li*XT_S + jt*16 + grp*4];
    }

    const int mt0 = wu, mt1 = wu + 4, mt2 = wu + 8;
    const int jlo = (wu == 0) ? 0 : (3*wu + 1);
    const int jhi = 3*wu + 4;

    f32x4 ao0 = {0.f,0.f,0.f,0.f}, aD0 = {0.f,0.f,0.f,0.f};
    f32x4 ao1 = {0.f,0.f,0.f,0.f}, aD1 = {0.f,0.f,0.f,0.f};
    f32x4 ao2 = {0.f,0.f,0.f,0.f}, aD2 = {0.f,0.f,0.f,0.f};
    f32x4 ao3 = {0.f,0.f,0.f,0.f}, aD3 = {0.f,0.f,0.f,0.f};

    #pragma unroll
    for (int jt = 0; jt < 13; jt++) {
        const f32x4 zc = {0.f, 0.f, 0.f, 0.f};
        // 3 independent S-mfma chains launch together
        f32x4 s0 = mfma16(kfr[jt], qf0, zc);
        f32x4 s1 = mfma16(kfr[jt], qf1, zc);
        f32x4 s2 = mfma16(kfr[jt], qf2, zc);
        bf16_4 p0, p1, p2;
        #pragma unroll
        for (int r = 0; r < 4; r++) {
            float v0 = __builtin_amdgcn_exp2f(s0[r]);
            float v1 = __builtin_amdgcn_exp2f(s1[r]);
            float v2 = __builtin_amdgcn_exp2f(s2[r]);
            if (jt == 12 && grp >= 2) { v0 = 0.f; v1 = 0.f; v2 = 0.f; }
            if (jt == mt0 && dr == r) v0 = 1.0f;
            if (jt == mt1 && dr == r) v1 = 1.0f;
            if (jt == mt2 && dr == r) v2 = 1.0f;
            p0[r] = (__bf16)v0; p1[r] = (__bf16)v1; p2[r] = (__bf16)v2;
        }
        aD0 = mfma16(p0, onesb, aD0);  ao0 = mfma16(p0, xbr[jt], ao0);
        aD1 = mfma16(p1, onesb, aD1);  ao1 = mfma16(p1, xbr[jt], ao1);
        aD2 = mfma16(p2, onesb, aD2);  ao2 = mfma16(p2, xbr[jt], ao2);
        // tile 12: this wave's jt slice (scalar guard)
        if (jt >= jlo && jt < jhi) {
            f32x4 s3 = mfma16(kfr[jt], qf12, zc);
            bf16_4 p3;
            #pragma unroll
            for (int r = 0; r < 4; r++) {
                float v3 = __builtin_amdgcn_exp2f(s3[r]);
                if (jt == 12 && grp >= 2) v3 = 0.f;
                if (jt == 12 && dr == r)  v3 = 1.0f;
                p3[r] = (__bf16)v3;
            }
            aD3 = mfma16(p3, onesb, aD3);  ao3 = mfma16(p3, xbr[jt], ao3);
        }
    }

    float wsum = 0.f;
    #pragma unroll
    for (int r = 0; r < 4; r++) {
        wsum += ao0[r] * __builtin_amdgcn_rcpf(aD0[r]);
        wsum += ao1[r] * __builtin_amdgcn_rcpf(aD1[r]);
        wsum += ao2[r] * __builtin_amdgcn_rcpf(aD2[r]);
    }
    if (li == 0) {                            // aD3[r] uniform across li
        #pragma unroll
        for (int r = 0; r < 4; r++)
            tot12t[(grp*4 + r)*4 + w] = aD3[r];
    }
    __syncthreads();

    // combine tile-12: full denominator = sum of 4 wave partials
    #pragma unroll
    for (int r = 0; r < 4; r++) {
        const int q = grp*4 + r;                 // row 192+q
        const float4 p4 = *(const float4*)&tot12t[q*4];
        const float dsum = (p4.x + p4.y) + (p4.z + p4.w);
        if (192 + q < LSEQ)
            wsum += ao3[r] * __builtin_amdgcn_rcpf(dsum);
    }

    wsum += __shfl_xor(wsum, 16);
    wsum += __shfl_xor(wsum, 32);
    if (lane < DD) red[w][lane] = wsum;
    __syncthreads();

    // ============ epilogue prefetch: issue course-row loads under the MLP ======
    float4 ce0, ce1, ce2, ce3;
    if (t < NCC) {
        const int ci = course_set[b*NCC + t];
        const float* ce = &course_table[ci*DD];
        ce0 = *(const float4*)&ce[0];
        ce1 = *(const float4*)&ce[4];
        ce2 = *(const float4*)&ce[8];
        ce3 = *(const float4*)&ce[12];
    }

    // ============ phase 4: MLP in wave 0 via shuffles ==========================
    if (w == 0) {
        const float ue  = rows_pre[li];
        const float seq = (red[0][li] + red[1][li] + red[2][li] + red[3][li]) * (1.0f / LSEQ);
        float uts = 0.f;
        #pragma unroll
        for (int i = 0; i < LTT; i++)  uts += rows_pre[16 + i*16 + li];
        float uss = 0.f;
        #pragma unroll
        for (int i = 0; i < LSCH; i++) uss += rows_pre[176 + i*16 + li];
        const float agg = (seq + uts / lens[0] + uss / lens[1]) * (1.0f / 3.0f);
        float a1 = gst[512 + li];
        #pragma unroll
        for (int k = 0; k < 16; k++) a1 = fmaf(__shfl(ue,  k), gst[k*DD + li], a1);
        #pragma unroll
        for (int k = 0; k < 16; k++) a1 = fmaf(__shfl(agg, k), gst[(16 + k)*DD + li], a1);
        const float hidv = fmaxf(a1, 0.f);
        float a2 = gst[784 + li];
        #pragma unroll
        for (int k = 0; k < 16; k++) a2 = fmaf(__shfl(hidv, k), gst[528 + k*DD + li], a2);
        if (lane < DD) uf[lane] = a2;
    }
    __syncthreads();

    // ============ epilogue: dot with prefetched rows ===========================
    if (t < NCC) {
        const float4 u0 = *(const float4*)&uf[0];
        const float4 u1 = *(const float4*)&uf[4];
        const float4 u2 = *(const float4*)&uf[8];
        const float4 u3 = *(const float4*)&uf[12];
        float s = ce0.x*u0.x + ce0.y*u0.y + ce0.z*u0.z + ce0.w*u0.w;
        s      += ce1.x*u1.x + ce1.y*u1.y + ce1.z*u1.z + ce1.w*u1.w;
        s      += ce2.x*u2.x + ce2.y*u2.y + ce2.z*u2.z + ce2.w*u2.w;
        s      += ce3.x*u3.x + ce3.y*u3.y + ce3.z*u3.z + ce3.w*u3.w;
        out[b*NCC + t] = s;
    }
}

extern "C" void kernel_launch(void* const* d_in, const int* in_sizes, int n_in,
                              void* d_out, int out_size, void* d_ws, size_t ws_size,
                              hipStream_t stream) {
    const int*   user_idx         = (const int*)  d_in[0];
    const int*   user_sequence    = (const int*)  d_in[1];
    const int*   user_teachers    = (const int*)  d_in[2];
    const int*   user_school      = (const int*)  d_in[3];
    const float* user_len_teacher = (const float*)d_in[5];
    const float* user_len_school  = (const float*)d_in[6];
    const int*   course_set       = (const int*)  d_in[7];
    const float* user_table       = (const float*)d_in[13];
    const float* course_table     = (const float*)d_in[14];
    const float* teacher_table    = (const float*)d_in[15];
    const float* school_table     = (const float*)d_in[16];
    const float* Qw  = (const float*)d_in[17];
    const float* Qb  = (const float*)d_in[18];
    const float* Kw  = (const float*)d_in[19];
    const float* Kb  = (const float*)d_in[20];
    const float* g1w = (const float*)d_in[21];
    const float* g1b = (const float*)d_in[22];
    const float* g2w = (const float*)d_in[23];
    const float* g2b = (const float*)d_in[24];

    float* outp = (float*)d_out;

    hipLaunchKernelGGL(hin_kernel, dim3(NBATCH), dim3(256), 0, stream,
                       user_idx, user_sequence, user_teachers, user_school,
                       user_len_teacher, user_len_school, course_set,
                       user_table, course_table, teacher_table, school_table,
                       Qw, Qb, Kw, Kb, g1w, g1b, g2w, g2b, outp);
}